// Round 2
// baseline (1351.394 us; speedup 1.0000x reference)
//
#include <hip/hip_runtime.h>

#define N_NODES 100000
#define N_EDGES 1200000
#define NG 512

typedef float f32;

// ---------------- dtype probe: int64 vs int32 edge/batch arrays ----------------
// For int64 data (values < 2^31), every odd 32-bit word is 0. If ANY sampled
// odd word is nonzero -> int32. flag: 0 = int64, 1 = int32.
__global__ void k_detect(const int* __restrict__ w, int* __restrict__ flag) {
  int t = threadIdx.x;
  int acc = 0;
  #pragma unroll
  for (int k = 0; k < 8; ++k) acc |= w[(t * 8 + k) * 2 + 1];
  if (acc) atomicOr(flag, 1);
}

// ---------------- CSR build ----------------
__global__ void k_count(const int* __restrict__ w, const int* __restrict__ flag,
                        int* __restrict__ deg) {
  int e = blockIdx.x * 256 + threadIdx.x;
  if (e >= N_EDGES) return;
  int d = flag[0] ? w[N_EDGES + e] : w[2 * (N_EDGES + e)];
  atomicAdd(&deg[d], 1);
}

__global__ void k_scan1(const int* __restrict__ deg, int* __restrict__ incl, int* __restrict__ bsums) {
  __shared__ int sd[256];
  int t = threadIdx.x, b = blockIdx.x;
  int base = b * 1024 + t * 4;
  int v0 = (base + 0 < N_NODES) ? deg[base + 0] : 0;
  int v1 = (base + 1 < N_NODES) ? deg[base + 1] : 0;
  int v2 = (base + 2 < N_NODES) ? deg[base + 2] : 0;
  int v3 = (base + 3 < N_NODES) ? deg[base + 3] : 0;
  int s = v0 + v1 + v2 + v3;
  sd[t] = s; __syncthreads();
  for (int off = 1; off < 256; off <<= 1) {
    int x = (t >= off) ? sd[t - off] : 0; __syncthreads();
    sd[t] += x; __syncthreads();
  }
  int run = sd[t] - s;
  run += v0; if (base + 0 < N_NODES) incl[base + 0] = run;
  run += v1; if (base + 1 < N_NODES) incl[base + 1] = run;
  run += v2; if (base + 2 < N_NODES) incl[base + 2] = run;
  run += v3; if (base + 3 < N_NODES) incl[base + 3] = run;
  if (t == 255) bsums[b] = sd[255];
}

__global__ void k_scan2(int* __restrict__ bsums, int nb) {
  __shared__ int sd[128];
  int t = threadIdx.x;
  int v = (t < nb) ? bsums[t] : 0;
  sd[t] = v; __syncthreads();
  for (int off = 1; off < 128; off <<= 1) {
    int x = (t >= off) ? sd[t - off] : 0; __syncthreads();
    sd[t] += x; __syncthreads();
  }
  if (t < nb) bsums[t] = sd[t] - v;
}

__global__ void k_scan3(const int* __restrict__ incl, const int* __restrict__ bsums,
                        int* __restrict__ offs, int* __restrict__ cursor) {
  int i = blockIdx.x * 256 + threadIdx.x;
  if (i >= N_NODES) return;
  int start = (i == 0) ? 0 : (incl[i - 1] + bsums[(i - 1) >> 10]);
  offs[i] = start; cursor[i] = start;
  if (i == N_NODES - 1) offs[N_NODES] = incl[i] + bsums[i >> 10];
}

__global__ void k_fill(const int* __restrict__ w, const int* __restrict__ flag,
                       int* __restrict__ cursor, int* __restrict__ csr) {
  int e = blockIdx.x * 256 + threadIdx.x;
  if (e >= N_EDGES) return;
  int is32 = flag[0];
  int s = is32 ? w[e] : w[2 * e];
  int d = is32 ? w[N_EDGES + e] : w[2 * (N_EDGES + e)];
  int p = atomicAdd(&cursor[d], 1);
  csr[p] = s;
}

// ---------------- fused GIN layer: agg + MLP + BN stats ----------------
#define GEMM_STEP(Ws) { \
    float4 w0 = *(const float4*)&Ws[(f + 0) * 64 + c0]; \
    float4 w1 = *(const float4*)&Ws[(f + 1) * 64 + c0]; \
    float4 w2 = *(const float4*)&Ws[(f + 2) * 64 + c0]; \
    float4 w3 = *(const float4*)&Ws[(f + 3) * 64 + c0]; \
    _Pragma("unroll") \
    for (int i = 0; i < 4; ++i) { \
      float4 a = *(const float4*)&As[(r0 + i) * 68 + f]; \
      acc[i][0] = fmaf(a.x, w0.x, fmaf(a.y, w1.x, fmaf(a.z, w2.x, fmaf(a.w, w3.x, acc[i][0])))); \
      acc[i][1] = fmaf(a.x, w0.y, fmaf(a.y, w1.y, fmaf(a.z, w2.y, fmaf(a.w, w3.y, acc[i][1])))); \
      acc[i][2] = fmaf(a.x, w0.z, fmaf(a.y, w1.z, fmaf(a.z, w2.z, fmaf(a.w, w3.z, acc[i][2])))); \
      acc[i][3] = fmaf(a.x, w0.w, fmaf(a.y, w1.w, fmaf(a.z, w2.w, fmaf(a.w, w3.w, acc[i][3])))); \
    } \
  }

__global__ __launch_bounds__(256) void k_layer(
    const f32* __restrict__ hin, f32* __restrict__ yout,
    const int* __restrict__ offs, const int* __restrict__ csr,
    const f32* __restrict__ W1, const f32* __restrict__ b1,
    const f32* __restrict__ W2, const f32* __restrict__ b2,
    f32* __restrict__ stsum, f32* __restrict__ stsq)
{
  __shared__ f32 As[64 * 68];
  __shared__ f32 W1s[4096];
  __shared__ f32 W2s[4096];
  __shared__ f32 b1s[64], b2s[64], blks[64], blkq[64];
  const int t = threadIdx.x;
  for (int i = t; i < 4096; i += 256) { W1s[i] = W1[i]; W2s[i] = W2[i]; }
  if (t < 64) { b1s[t] = b1[t]; b2s[t] = b2[t]; blks[t] = 0.f; blkq[t] = 0.f; }
  const int base = blockIdx.x * 64;
  const int wave = t >> 6, lane = t & 63;
  #pragma unroll 1
  for (int r = wave * 16; r < wave * 16 + 16; ++r) {
    int node = base + r;
    f32 z = 0.f;
    if (node < N_NODES) {
      z = hin[node * 64 + lane];
      int e0 = offs[node], e1 = offs[node + 1];
      for (int e = e0; e < e1; ++e) z += hin[csr[e] * 64 + lane];
    }
    As[r * 68 + lane] = z;
  }
  __syncthreads();
  const int r0 = (t >> 4) * 4, c0 = (t & 15) * 4;
  f32 acc[4][4];
  #pragma unroll
  for (int i = 0; i < 4; ++i) { acc[i][0] = acc[i][1] = acc[i][2] = acc[i][3] = 0.f; }
  #pragma unroll 4
  for (int f = 0; f < 64; f += 4) GEMM_STEP(W1s)
  __syncthreads();
  #pragma unroll
  for (int i = 0; i < 4; ++i) {
    float4 v;
    v.x = fmaxf(acc[i][0] + b1s[c0 + 0], 0.f);
    v.y = fmaxf(acc[i][1] + b1s[c0 + 1], 0.f);
    v.z = fmaxf(acc[i][2] + b1s[c0 + 2], 0.f);
    v.w = fmaxf(acc[i][3] + b1s[c0 + 3], 0.f);
    *(float4*)&As[(r0 + i) * 68 + c0] = v;
  }
  __syncthreads();
  #pragma unroll
  for (int i = 0; i < 4; ++i) { acc[i][0] = acc[i][1] = acc[i][2] = acc[i][3] = 0.f; }
  #pragma unroll 4
  for (int f = 0; f < 64; f += 4) GEMM_STEP(W2s)
  f32 ps0 = 0, ps1 = 0, ps2 = 0, ps3 = 0, pq0 = 0, pq1 = 0, pq2 = 0, pq3 = 0;
  #pragma unroll
  for (int i = 0; i < 4; ++i) {
    int node = base + r0 + i;
    if (node < N_NODES) {
      f32 y0 = acc[i][0] + b2s[c0 + 0];
      f32 y1 = acc[i][1] + b2s[c0 + 1];
      f32 y2 = acc[i][2] + b2s[c0 + 2];
      f32 y3 = acc[i][3] + b2s[c0 + 3];
      float4 v = { y0, y1, y2, y3 };
      *(float4*)&yout[node * 64 + c0] = v;
      ps0 += y0; pq0 += y0 * y0;
      ps1 += y1; pq1 += y1 * y1;
      ps2 += y2; pq2 += y2 * y2;
      ps3 += y3; pq3 += y3 * y3;
    }
  }
  atomicAdd(&blks[c0 + 0], ps0); atomicAdd(&blkq[c0 + 0], pq0);
  atomicAdd(&blks[c0 + 1], ps1); atomicAdd(&blkq[c0 + 1], pq1);
  atomicAdd(&blks[c0 + 2], ps2); atomicAdd(&blkq[c0 + 2], pq2);
  atomicAdd(&blks[c0 + 3], ps3); atomicAdd(&blkq[c0 + 3], pq3);
  __syncthreads();
  if (t < 64) { atomicAdd(&stsum[t], blks[t]); atomicAdd(&stsq[t], blkq[t]); }
}

// ---------------- BN finalize ----------------
__global__ void k_hfin(const f32* __restrict__ st, const f32* __restrict__ g,
                       const f32* __restrict__ b, f32* __restrict__ ss, f32 invn, int d) {
  int t = threadIdx.x;
  if (t < d) {
    f32 m = st[t] * invn;
    f32 var = st[64 + t] * invn - m * m;
    f32 inv = rsqrtf(var + 1e-5f);
    f32 sc = g[t] * inv;
    ss[t] = sc;
    ss[64 + t] = b[t] - m * sc;
  }
}

// ---------------- BN apply + relu ----------------
__global__ void k_bnapply(const f32* y, f32* h, const f32* __restrict__ ss) {
  int i = blockIdx.x * 256 + threadIdx.x;
  if (i >= N_NODES * 16) return;
  int c0 = (i & 15) * 4;
  float4 v = ((const float4*)y)[i];
  v.x = fmaxf(fmaf(v.x, ss[c0 + 0], ss[64 + c0 + 0]), 0.f);
  v.y = fmaxf(fmaf(v.y, ss[c0 + 1], ss[64 + c0 + 1]), 0.f);
  v.z = fmaxf(fmaf(v.z, ss[c0 + 2], ss[64 + c0 + 2]), 0.f);
  v.w = fmaxf(fmaf(v.w, ss[c0 + 3], ss[64 + c0 + 3]), 0.f);
  ((float4*)h)[i] = v;
}

// ---------------- global mean pool (batch sorted) ----------------
__global__ void k_pool(const f32* __restrict__ h, const int* __restrict__ bw,
                       const int* __restrict__ flag,
                       f32* __restrict__ gsum, f32* __restrict__ gcnt) {
  int wid = (blockIdx.x * blockDim.x + threadIdx.x) >> 6;
  int lane = threadIdx.x & 63;
  const int nw = (256 * 256) >> 6;
  const int per = (N_NODES + nw - 1) / nw;
  int s = wid * per; int e = s + per; if (e > N_NODES) e = N_NODES;
  if (s >= e) return;
  int is32 = flag[0];
  int g = is32 ? bw[s] : bw[2 * s];
  f32 acc = 0.f, cnt = 0.f;
  for (int i = s; i < e; ++i) {
    int gi = is32 ? bw[i] : bw[2 * i];
    if (gi != g) {
      atomicAdd(&gsum[g * 64 + lane], acc);
      if (lane == 0) atomicAdd(&gcnt[g], cnt);
      g = gi; acc = 0.f; cnt = 0.f;
    }
    acc += h[i * 64 + lane];
    cnt += 1.f;
  }
  atomicAdd(&gsum[g * 64 + lane], acc);
  if (lane == 0) atomicAdd(&gcnt[g], cnt);
}

// ---------------- head ----------------
__global__ __launch_bounds__(256) void k_head1(const f32* __restrict__ gsum, const f32* __restrict__ gcnt,
                                               const f32* __restrict__ W, const f32* __restrict__ bias,
                                               f32* __restrict__ p, f32* __restrict__ st) {
  __shared__ f32 Ws[4096];
  __shared__ f32 zs[4][64];
  __shared__ f32 bs[64], bq[64];
  int t = threadIdx.x;
  for (int i = t; i < 4096; i += 256) Ws[i] = W[i];
  if (t < 64) { bs[t] = 0.f; bq[t] = 0.f; }
  int wave = t >> 6, lane = t & 63;
  int row = blockIdx.x * 4 + wave;
  f32 z = gsum[row * 64 + lane] / fmaxf(gcnt[row], 1.f);
  zs[wave][lane] = z;
  __syncthreads();
  f32 y = bias[lane];
  for (int f = 0; f < 64; ++f) y = fmaf(zs[wave][f], Ws[f * 64 + lane], y);
  p[row * 64 + lane] = y;
  atomicAdd(&bs[lane], y);
  atomicAdd(&bq[lane], y * y);
  __syncthreads();
  if (t < 64) { atomicAdd(&st[t], bs[t]); atomicAdd(&st[64 + t], bq[t]); }
}

__global__ __launch_bounds__(256) void k_head2(const f32* __restrict__ p1, const f32* __restrict__ ss,
                                               const f32* __restrict__ W, const f32* __restrict__ bias,
                                               f32* __restrict__ p2, f32* __restrict__ st) {
  __shared__ f32 Ws[2048];
  __shared__ f32 zs[4][64];
  __shared__ f32 bs[32], bq[32];
  int t = threadIdx.x;
  for (int i = t; i < 2048; i += 256) Ws[i] = W[i];
  if (t < 32) { bs[t] = 0.f; bq[t] = 0.f; }
  int wave = t >> 6, lane = t & 63;
  int row = blockIdx.x * 4 + wave;
  f32 z = fmaxf(fmaf(p1[row * 64 + lane], ss[lane], ss[64 + lane]), 0.f);
  zs[wave][lane] = z;
  __syncthreads();
  if (lane < 32) {
    f32 y = bias[lane];
    for (int f = 0; f < 64; ++f) y = fmaf(zs[wave][f], Ws[f * 32 + lane], y);
    p2[row * 32 + lane] = y;
    atomicAdd(&bs[lane], y);
    atomicAdd(&bq[lane], y * y);
  }
  __syncthreads();
  if (t < 32) { atomicAdd(&st[t], bs[t]); atomicAdd(&st[64 + t], bq[t]); }
}

__global__ __launch_bounds__(256) void k_head3(const f32* __restrict__ p2, const f32* __restrict__ ss,
                                               const f32* __restrict__ W, const f32* __restrict__ bias,
                                               f32* __restrict__ out) {
  __shared__ f32 Ws[320];
  __shared__ f32 obs[10];
  __shared__ f32 zs[4][32];
  int t = threadIdx.x;
  for (int i = t; i < 320; i += 256) Ws[i] = W[i];   // FIX: full 320 fill
  if (t < 10) obs[t] = bias[t];
  int wave = t >> 6, lane = t & 63;
  int row = blockIdx.x * 4 + wave;
  if (lane < 32) zs[wave][lane] = fmaxf(fmaf(p2[row * 32 + lane], ss[lane], ss[64 + lane]), 0.f);
  __syncthreads();
  if (lane < 10) {
    f32 o = obs[lane];
    for (int f = 0; f < 32; ++f) o = fmaf(zs[wave][f], Ws[f * 10 + lane], o);
    out[row * 10 + lane] = o;
  }
}

extern "C" void kernel_launch(void* const* d_in, const int* in_sizes, int n_in,
                              void* d_out, int out_size, void* d_ws, size_t ws_size,
                              hipStream_t stream) {
  (void)in_sizes; (void)n_in; (void)out_size; (void)ws_size;
  const f32* x    = (const f32*)d_in[0];
  const int* eiw  = (const int*)d_in[1];   // words; dtype detected on device
  const int* btw  = (const int*)d_in[2];
  const f32* mw1  = (const f32*)d_in[3];
  const f32* mb1  = (const f32*)d_in[4];
  const f32* mw2  = (const f32*)d_in[5];
  const f32* mb2  = (const f32*)d_in[6];
  const f32* bng  = (const f32*)d_in[7];
  const f32* bnb  = (const f32*)d_in[8];
  const f32* hw1  = (const f32*)d_in[9];
  const f32* hb1  = (const f32*)d_in[10];
  const f32* hg1  = (const f32*)d_in[11];
  const f32* hbb1 = (const f32*)d_in[12];
  const f32* hw2  = (const f32*)d_in[13];
  const f32* hb2  = (const f32*)d_in[14];
  const f32* hg2  = (const f32*)d_in[15];
  const f32* hbb2 = (const f32*)d_in[16];
  const f32* ow   = (const f32*)d_in[17];
  const f32* ob   = (const f32*)d_in[18];
  f32* out = (f32*)d_out;

  int* deg    = (int*)d_ws;
  int* incl   = deg + N_NODES;
  int* bsums  = incl + N_NODES;       // 128
  int* flag   = bsums + 128;          // 4 (padded)
  int* offs   = flag + 4;             // 100001 -> pad 100004
  int* cursor = offs + 100004;
  int* csr    = cursor + N_NODES;     // 1.2M
  f32* hA     = (f32*)(csr + N_EDGES);
  f32* hB     = hA + N_NODES * 64;
  f32* stats  = hB + N_NODES * 64;    // 1024
  f32* ss     = stats + 1024;         // 128
  f32* ss2    = ss + 128;             // 128
  f32* gsum   = ss2 + 128;            // NG*64
  f32* gcnt   = gsum + NG * 64;       // NG
  f32* p1     = gcnt + NG;            // NG*64
  f32* p2     = p1 + NG * 64;         // NG*32

  hipMemsetAsync(deg, 0, N_NODES * sizeof(int), stream);
  hipMemsetAsync(flag, 0, sizeof(int), stream);
  hipMemsetAsync(stats, 0, 1024 * sizeof(f32), stream);
  hipMemsetAsync(gsum, 0, (NG * 64 + NG) * sizeof(f32), stream);

  k_detect<<<1, 256, 0, stream>>>(eiw, flag);
  k_count<<<(N_EDGES + 255) / 256, 256, 0, stream>>>(eiw, flag, deg);
  k_scan1<<<(N_NODES + 1023) / 1024, 256, 0, stream>>>(deg, incl, bsums);
  k_scan2<<<1, 128, 0, stream>>>(bsums, (N_NODES + 1023) / 1024);
  k_scan3<<<(N_NODES + 255) / 256, 256, 0, stream>>>(incl, bsums, offs, cursor);
  k_fill<<<(N_EDGES + 255) / 256, 256, 0, stream>>>(eiw, flag, cursor, csr);

  const int LGRID = (N_NODES + 63) / 64;
  const int AGRID = (N_NODES * 16 + 255) / 256;
  k_layer<<<LGRID, 256, 0, stream>>>(x,  hA, offs, csr, mw1,        mb1,       mw2,        mb2,       stats + 0,   stats + 64);
  k_hfin<<<1, 64, 0, stream>>>(stats + 0, bng + 0, bnb + 0, ss, 1.f / N_NODES, 64);
  k_bnapply<<<AGRID, 256, 0, stream>>>(hA, hA, ss);
  k_layer<<<LGRID, 256, 0, stream>>>(hA, hB, offs, csr, mw1 + 4096, mb1 + 64,  mw2 + 4096, mb2 + 64,  stats + 128, stats + 192);
  k_hfin<<<1, 64, 0, stream>>>(stats + 128, bng + 64, bnb + 64, ss, 1.f / N_NODES, 64);
  k_bnapply<<<AGRID, 256, 0, stream>>>(hB, hB, ss);
  k_layer<<<LGRID, 256, 0, stream>>>(hB, hA, offs, csr, mw1 + 8192, mb1 + 128, mw2 + 8192, mb2 + 128, stats + 256, stats + 320);
  k_hfin<<<1, 64, 0, stream>>>(stats + 256, bng + 128, bnb + 128, ss, 1.f / N_NODES, 64);
  k_bnapply<<<AGRID, 256, 0, stream>>>(hA, hA, ss);

  k_pool<<<256, 256, 0, stream>>>(hA, btw, flag, gsum, gcnt);
  k_head1<<<NG / 4, 256, 0, stream>>>(gsum, gcnt, hw1, hb1, p1, stats + 384);
  k_hfin<<<1, 64, 0, stream>>>(stats + 384, hg1, hbb1, ss, 1.f / NG, 64);
  k_head2<<<NG / 4, 256, 0, stream>>>(p1, ss, hw2, hb2, p2, stats + 512);
  k_hfin<<<1, 64, 0, stream>>>(stats + 512, hg2, hbb2, ss2, 1.f / NG, 32);
  k_head3<<<NG / 4, 256, 0, stream>>>(p2, ss2, ow, ob, out);
}

// Round 4
// 743.981 us; speedup vs baseline: 1.8164x; 1.8164x over previous
//
#include <hip/hip_runtime.h>

#define N_NODES 100000
#define N_EDGES 1200000
#define NG 512

typedef float f32;

// ---------------- dtype probe: int64 vs int32 edge/batch arrays ----------------
__global__ void k_detect(const int* __restrict__ w, int* __restrict__ flag) {
  int t = threadIdx.x;
  int acc = 0;
  #pragma unroll
  for (int k = 0; k < 8; ++k) acc |= w[(t * 8 + k) * 2 + 1];
  if (acc) atomicOr(flag, 1);
}

// ---------------- CSR build ----------------
__global__ void k_count(const int* __restrict__ w, const int* __restrict__ flag,
                        int* __restrict__ deg) {
  int e = blockIdx.x * 256 + threadIdx.x;
  if (e >= N_EDGES) return;
  int d = flag[0] ? w[N_EDGES + e] : w[2 * (N_EDGES + e)];
  atomicAdd(&deg[d], 1);
}

__global__ void k_scan1(const int* __restrict__ deg, int* __restrict__ incl, int* __restrict__ bsums) {
  __shared__ int sd[256];
  int t = threadIdx.x, b = blockIdx.x;
  int base = b * 1024 + t * 4;
  int v0 = (base + 0 < N_NODES) ? deg[base + 0] : 0;
  int v1 = (base + 1 < N_NODES) ? deg[base + 1] : 0;
  int v2 = (base + 2 < N_NODES) ? deg[base + 2] : 0;
  int v3 = (base + 3 < N_NODES) ? deg[base + 3] : 0;
  int s = v0 + v1 + v2 + v3;
  sd[t] = s; __syncthreads();
  for (int off = 1; off < 256; off <<= 1) {
    int x = (t >= off) ? sd[t - off] : 0; __syncthreads();
    sd[t] += x; __syncthreads();
  }
  int run = sd[t] - s;
  run += v0; if (base + 0 < N_NODES) incl[base + 0] = run;
  run += v1; if (base + 1 < N_NODES) incl[base + 1] = run;
  run += v2; if (base + 2 < N_NODES) incl[base + 2] = run;
  run += v3; if (base + 3 < N_NODES) incl[base + 3] = run;
  if (t == 255) bsums[b] = sd[255];
}

__global__ void k_scan2(int* __restrict__ bsums, int nb) {
  __shared__ int sd[128];
  int t = threadIdx.x;
  int v = (t < nb) ? bsums[t] : 0;
  sd[t] = v; __syncthreads();
  for (int off = 1; off < 128; off <<= 1) {
    int x = (t >= off) ? sd[t - off] : 0; __syncthreads();
    sd[t] += x; __syncthreads();
  }
  if (t < nb) bsums[t] = sd[t] - v;
}

__global__ void k_scan3(const int* __restrict__ incl, const int* __restrict__ bsums,
                        int* __restrict__ offs, int* __restrict__ cursor) {
  int i = blockIdx.x * 256 + threadIdx.x;
  if (i >= N_NODES) return;
  int start = (i == 0) ? 0 : (incl[i - 1] + bsums[(i - 1) >> 10]);
  offs[i] = start; cursor[i] = start;
  if (i == N_NODES - 1) offs[N_NODES] = incl[i] + bsums[i >> 10];
}

__global__ void k_fill(const int* __restrict__ w, const int* __restrict__ flag,
                       int* __restrict__ cursor, int* __restrict__ csr) {
  int e = blockIdx.x * 256 + threadIdx.x;
  if (e >= N_EDGES) return;
  int is32 = flag[0];
  int s = is32 ? w[e] : w[2 * e];
  int d = is32 ? w[N_EDGES + e] : w[2 * (N_EDGES + e)];
  int p = atomicAdd(&cursor[d], 1);
  csr[p] = s;
}

// ---------------- aggregation: one wave per node, 4 edge-slots x 16 f-lanes ----
__global__ __launch_bounds__(256) void k_agg(const f32* __restrict__ hin,
                                             f32* __restrict__ z,
                                             const int* __restrict__ offs,
                                             const int* __restrict__ csr) {
  int wid = blockIdx.x * 4 + (threadIdx.x >> 6);
  int lane = threadIdx.x & 63;
  int slot = lane >> 4;          // 0..3 edge slot
  int fl = (lane & 15) << 2;     // feature offset (float4)
  int e0 = offs[wid], e1 = offs[wid + 1];
  float4 a0 = {0.f, 0.f, 0.f, 0.f}, a1 = {0.f, 0.f, 0.f, 0.f};
  int e = e0 + slot;
  for (; e + 4 < e1; e += 8) {
    int s0 = csr[e], s1 = csr[e + 4];
    float4 v0 = *(const float4*)&hin[s0 * 64 + fl];
    float4 v1 = *(const float4*)&hin[s1 * 64 + fl];
    a0.x += v0.x; a0.y += v0.y; a0.z += v0.z; a0.w += v0.w;
    a1.x += v1.x; a1.y += v1.y; a1.z += v1.z; a1.w += v1.w;
  }
  if (e < e1) {
    int s0 = csr[e];
    float4 v0 = *(const float4*)&hin[s0 * 64 + fl];
    a0.x += v0.x; a0.y += v0.y; a0.z += v0.z; a0.w += v0.w;
  }
  a0.x += a1.x; a0.y += a1.y; a0.z += a1.z; a0.w += a1.w;
  a0.x += __shfl_xor(a0.x, 16); a0.y += __shfl_xor(a0.y, 16);
  a0.z += __shfl_xor(a0.z, 16); a0.w += __shfl_xor(a0.w, 16);
  a0.x += __shfl_xor(a0.x, 32); a0.y += __shfl_xor(a0.y, 32);
  a0.z += __shfl_xor(a0.z, 32); a0.w += __shfl_xor(a0.w, 32);
  if (slot == 0) {
    float4 s = *(const float4*)&hin[wid * 64 + fl];
    float4 o = { a0.x + s.x, a0.y + s.y, a0.z + s.z, a0.w + s.w };
    *(float4*)&z[wid * 64 + fl] = o;
  }
}

// ---------------- MLP: 2 GEMMs + BN stats (64-row tiles, in-place z->y) -------
#define GEMM_STEP(Ws) { \
    float4 w0 = *(const float4*)&Ws[(f + 0) * 64 + c0]; \
    float4 w1 = *(const float4*)&Ws[(f + 1) * 64 + c0]; \
    float4 w2 = *(const float4*)&Ws[(f + 2) * 64 + c0]; \
    float4 w3 = *(const float4*)&Ws[(f + 3) * 64 + c0]; \
    _Pragma("unroll") \
    for (int i = 0; i < 4; ++i) { \
      float4 a = *(const float4*)&As[(r0 + i) * 68 + f]; \
      acc[i][0] = fmaf(a.x, w0.x, fmaf(a.y, w1.x, fmaf(a.z, w2.x, fmaf(a.w, w3.x, acc[i][0])))); \
      acc[i][1] = fmaf(a.x, w0.y, fmaf(a.y, w1.y, fmaf(a.z, w2.y, fmaf(a.w, w3.y, acc[i][1])))); \
      acc[i][2] = fmaf(a.x, w0.z, fmaf(a.y, w1.z, fmaf(a.z, w2.z, fmaf(a.w, w3.z, acc[i][2])))); \
      acc[i][3] = fmaf(a.x, w0.w, fmaf(a.y, w1.w, fmaf(a.z, w2.w, fmaf(a.w, w3.w, acc[i][3])))); \
    } \
  }

__global__ __launch_bounds__(256) void k_mlp(
    const f32* __restrict__ zin, f32* __restrict__ yout,
    const f32* __restrict__ W1, const f32* __restrict__ b1,
    const f32* __restrict__ W2, const f32* __restrict__ b2,
    f32* __restrict__ stsum, f32* __restrict__ stsq)
{
  __shared__ f32 As[64 * 68];
  __shared__ f32 W1s[4096];
  __shared__ f32 W2s[4096];
  __shared__ f32 b1s[64], b2s[64], blks[64], blkq[64];
  const int t = threadIdx.x;
  for (int i = t; i < 4096; i += 256) { W1s[i] = W1[i]; W2s[i] = W2[i]; }
  if (t < 64) { b1s[t] = b1[t]; b2s[t] = b2[t]; blks[t] = 0.f; blkq[t] = 0.f; }
  const int base = blockIdx.x * 64;
  #pragma unroll
  for (int p = 0; p < 4; ++p) {
    int elem = p * 1024 + t * 4;
    int row = elem >> 6, col = elem & 63;
    *(float4*)&As[row * 68 + col] = *(const float4*)&zin[base * 64 + elem];
  }
  __syncthreads();
  const int r0 = (t >> 4) * 4, c0 = (t & 15) * 4;
  f32 acc[4][4];
  #pragma unroll
  for (int i = 0; i < 4; ++i) { acc[i][0] = acc[i][1] = acc[i][2] = acc[i][3] = 0.f; }
  #pragma unroll 4
  for (int f = 0; f < 64; f += 4) GEMM_STEP(W1s)
  __syncthreads();
  #pragma unroll
  for (int i = 0; i < 4; ++i) {
    float4 v;
    v.x = fmaxf(acc[i][0] + b1s[c0 + 0], 0.f);
    v.y = fmaxf(acc[i][1] + b1s[c0 + 1], 0.f);
    v.z = fmaxf(acc[i][2] + b1s[c0 + 2], 0.f);
    v.w = fmaxf(acc[i][3] + b1s[c0 + 3], 0.f);
    *(float4*)&As[(r0 + i) * 68 + c0] = v;
  }
  __syncthreads();
  #pragma unroll
  for (int i = 0; i < 4; ++i) { acc[i][0] = acc[i][1] = acc[i][2] = acc[i][3] = 0.f; }
  #pragma unroll 4
  for (int f = 0; f < 64; f += 4) GEMM_STEP(W2s)
  f32 ps0 = 0, ps1 = 0, ps2 = 0, ps3 = 0, pq0 = 0, pq1 = 0, pq2 = 0, pq3 = 0;
  #pragma unroll
  for (int i = 0; i < 4; ++i) {
    int node = base + r0 + i;
    if (node < N_NODES) {
      f32 y0 = acc[i][0] + b2s[c0 + 0];
      f32 y1 = acc[i][1] + b2s[c0 + 1];
      f32 y2 = acc[i][2] + b2s[c0 + 2];
      f32 y3 = acc[i][3] + b2s[c0 + 3];
      float4 v = { y0, y1, y2, y3 };
      *(float4*)&yout[node * 64 + c0] = v;
      ps0 += y0; pq0 += y0 * y0;
      ps1 += y1; pq1 += y1 * y1;
      ps2 += y2; pq2 += y2 * y2;
      ps3 += y3; pq3 += y3 * y3;
    }
  }
  atomicAdd(&blks[c0 + 0], ps0); atomicAdd(&blkq[c0 + 0], pq0);
  atomicAdd(&blks[c0 + 1], ps1); atomicAdd(&blkq[c0 + 1], pq1);
  atomicAdd(&blks[c0 + 2], ps2); atomicAdd(&blkq[c0 + 2], pq2);
  atomicAdd(&blks[c0 + 3], ps3); atomicAdd(&blkq[c0 + 3], pq3);
  __syncthreads();
  if (t < 64) { atomicAdd(&stsum[t], blks[t]); atomicAdd(&stsq[t], blkq[t]); }
}

// ---------------- BN finalize ----------------
__global__ void k_hfin(const f32* __restrict__ st, const f32* __restrict__ g,
                       const f32* __restrict__ b, f32* __restrict__ ss, f32 invn, int d) {
  int t = threadIdx.x;
  if (t < d) {
    f32 m = st[t] * invn;
    f32 var = st[64 + t] * invn - m * m;
    f32 inv = rsqrtf(var + 1e-5f);
    f32 sc = g[t] * inv;
    ss[t] = sc;
    ss[64 + t] = b[t] - m * sc;
  }
}

// ---------------- BN apply + relu ----------------
__global__ void k_bnapply(const f32* y, f32* h, const f32* __restrict__ ss) {
  int i = blockIdx.x * 256 + threadIdx.x;
  if (i >= N_NODES * 16) return;
  int c0 = (i & 15) * 4;
  float4 v = ((const float4*)y)[i];
  v.x = fmaxf(fmaf(v.x, ss[c0 + 0], ss[64 + c0 + 0]), 0.f);
  v.y = fmaxf(fmaf(v.y, ss[c0 + 1], ss[64 + c0 + 1]), 0.f);
  v.z = fmaxf(fmaf(v.z, ss[c0 + 2], ss[64 + c0 + 2]), 0.f);
  v.w = fmaxf(fmaf(v.w, ss[c0 + 3], ss[64 + c0 + 3]), 0.f);
  ((float4*)h)[i] = v;
}

// ---------------- global mean pool (batch sorted) ----------------
__global__ void k_pool(const f32* __restrict__ h, const int* __restrict__ bw,
                       const int* __restrict__ flag,
                       f32* __restrict__ gsum, f32* __restrict__ gcnt) {
  int wid = (blockIdx.x * blockDim.x + threadIdx.x) >> 6;
  int lane = threadIdx.x & 63;
  const int nw = (256 * 256) >> 6;
  const int per = (N_NODES + nw - 1) / nw;
  int s = wid * per; int e = s + per; if (e > N_NODES) e = N_NODES;
  if (s >= e) return;
  int is32 = flag[0];
  int g = is32 ? bw[s] : bw[2 * s];
  f32 acc = 0.f, cnt = 0.f;
  for (int i = s; i < e; ++i) {
    int gi = is32 ? bw[i] : bw[2 * i];
    if (gi != g) {
      atomicAdd(&gsum[g * 64 + lane], acc);
      if (lane == 0) atomicAdd(&gcnt[g], cnt);
      g = gi; acc = 0.f; cnt = 0.f;
    }
    acc += h[i * 64 + lane];
    cnt += 1.f;
  }
  atomicAdd(&gsum[g * 64 + lane], acc);
  if (lane == 0) atomicAdd(&gcnt[g], cnt);
}

// ---------------- head ----------------
__global__ __launch_bounds__(256) void k_head1(const f32* __restrict__ gsum, const f32* __restrict__ gcnt,
                                               const f32* __restrict__ W, const f32* __restrict__ bias,
                                               f32* __restrict__ p, f32* __restrict__ st) {
  __shared__ f32 Ws[4096];
  __shared__ f32 zs[4][64];
  __shared__ f32 bs[64], bq[64];
  int t = threadIdx.x;
  for (int i = t; i < 4096; i += 256) Ws[i] = W[i];
  if (t < 64) { bs[t] = 0.f; bq[t] = 0.f; }
  int wave = t >> 6, lane = t & 63;
  int row = blockIdx.x * 4 + wave;
  f32 z = gsum[row * 64 + lane] / fmaxf(gcnt[row], 1.f);
  zs[wave][lane] = z;
  __syncthreads();
  f32 y = bias[lane];
  for (int f = 0; f < 64; ++f) y = fmaf(zs[wave][f], Ws[f * 64 + lane], y);
  p[row * 64 + lane] = y;
  atomicAdd(&bs[lane], y);
  atomicAdd(&bq[lane], y * y);
  __syncthreads();
  if (t < 64) { atomicAdd(&st[t], bs[t]); atomicAdd(&st[64 + t], bq[t]); }
}

__global__ __launch_bounds__(256) void k_head2(const f32* __restrict__ p1, const f32* __restrict__ ss,
                                               const f32* __restrict__ W, const f32* __restrict__ bias,
                                               f32* __restrict__ p2, f32* __restrict__ st) {
  __shared__ f32 Ws[2048];
  __shared__ f32 zs[4][64];
  __shared__ f32 bs[32], bq[32];
  int t = threadIdx.x;
  for (int i = t; i < 2048; i += 256) Ws[i] = W[i];
  if (t < 32) { bs[t] = 0.f; bq[t] = 0.f; }
  int wave = t >> 6, lane = t & 63;
  int row = blockIdx.x * 4 + wave;
  f32 z = fmaxf(fmaf(p1[row * 64 + lane], ss[lane], ss[64 + lane]), 0.f);
  zs[wave][lane] = z;
  __syncthreads();
  if (lane < 32) {
    f32 y = bias[lane];
    for (int f = 0; f < 64; ++f) y = fmaf(zs[wave][f], Ws[f * 32 + lane], y);
    p2[row * 32 + lane] = y;
    atomicAdd(&bs[lane], y);
    atomicAdd(&bq[lane], y * y);
  }
  __syncthreads();
  if (t < 32) { atomicAdd(&st[t], bs[t]); atomicAdd(&st[64 + t], bq[t]); }
}

__global__ __launch_bounds__(256) void k_head3(const f32* __restrict__ p2, const f32* __restrict__ ss,
                                               const f32* __restrict__ W, const f32* __restrict__ bias,
                                               f32* __restrict__ out) {
  __shared__ f32 Ws[320];
  __shared__ f32 obs[10];
  __shared__ f32 zs[4][32];
  int t = threadIdx.x;
  for (int i = t; i < 320; i += 256) Ws[i] = W[i];
  if (t < 10) obs[t] = bias[t];
  int wave = t >> 6, lane = t & 63;
  int row = blockIdx.x * 4 + wave;
  if (lane < 32) zs[wave][lane] = fmaxf(fmaf(p2[row * 32 + lane], ss[lane], ss[64 + lane]), 0.f);
  __syncthreads();
  if (lane < 10) {
    f32 o = obs[lane];
    for (int f = 0; f < 32; ++f) o = fmaf(zs[wave][f], Ws[f * 10 + lane], o);
    out[row * 10 + lane] = o;
  }
}

extern "C" void kernel_launch(void* const* d_in, const int* in_sizes, int n_in,
                              void* d_out, int out_size, void* d_ws, size_t ws_size,
                              hipStream_t stream) {
  (void)in_sizes; (void)n_in; (void)out_size; (void)ws_size;
  const f32* x    = (const f32*)d_in[0];
  const int* eiw  = (const int*)d_in[1];
  const int* btw  = (const int*)d_in[2];
  const f32* mw1  = (const f32*)d_in[3];
  const f32* mb1  = (const f32*)d_in[4];
  const f32* mw2  = (const f32*)d_in[5];
  const f32* mb2  = (const f32*)d_in[6];
  const f32* bng  = (const f32*)d_in[7];
  const f32* bnb  = (const f32*)d_in[8];
  const f32* hw1  = (const f32*)d_in[9];
  const f32* hb1  = (const f32*)d_in[10];
  const f32* hg1  = (const f32*)d_in[11];
  const f32* hbb1 = (const f32*)d_in[12];
  const f32* hw2  = (const f32*)d_in[13];
  const f32* hb2  = (const f32*)d_in[14];
  const f32* hg2  = (const f32*)d_in[15];
  const f32* hbb2 = (const f32*)d_in[16];
  const f32* ow   = (const f32*)d_in[17];
  const f32* ob   = (const f32*)d_in[18];
  f32* out = (f32*)d_out;

  int* deg    = (int*)d_ws;
  int* incl   = deg + N_NODES;
  int* bsums  = incl + N_NODES;       // 128
  int* flag   = bsums + 128;          // 4
  int* offs   = flag + 4;             // 100001 -> pad 100004
  int* cursor = offs + 100004;
  int* csr    = cursor + N_NODES;     // 1.2M
  f32* hbuf   = (f32*)(csr + N_EDGES);
  f32* zbuf   = hbuf + N_NODES * 64;
  f32* stats  = zbuf + N_NODES * 64;  // 1024
  f32* ss     = stats + 1024;         // 128
  f32* ss2    = ss + 128;             // 128
  f32* gsum   = ss2 + 128;            // NG*64
  f32* gcnt   = gsum + NG * 64;       // NG
  f32* p1     = gcnt + NG;            // NG*64
  f32* p2     = p1 + NG * 64;         // NG*32

  hipMemsetAsync(deg, 0, N_NODES * sizeof(int), stream);
  hipMemsetAsync(flag, 0, sizeof(int), stream);
  hipMemsetAsync(stats, 0, 1024 * sizeof(f32), stream);
  hipMemsetAsync(gsum, 0, (NG * 64 + NG) * sizeof(f32), stream);

  k_detect<<<1, 256, 0, stream>>>(eiw, flag);
  k_count<<<(N_EDGES + 255) / 256, 256, 0, stream>>>(eiw, flag, deg);
  k_scan1<<<(N_NODES + 1023) / 1024, 256, 0, stream>>>(deg, incl, bsums);
  k_scan2<<<1, 128, 0, stream>>>(bsums, (N_NODES + 1023) / 1024);
  k_scan3<<<(N_NODES + 255) / 256, 256, 0, stream>>>(incl, bsums, offs, cursor);
  k_fill<<<(N_EDGES + 255) / 256, 256, 0, stream>>>(eiw, flag, cursor, csr);

  const int AGG_GRID = N_NODES / 4;            // 1 wave per node
  const int MLP_GRID = (N_NODES + 63) / 64;
  const int APP_GRID = (N_NODES * 16 + 255) / 256;

  // layer 0
  k_agg<<<AGG_GRID, 256, 0, stream>>>(x, zbuf, offs, csr);
  k_mlp<<<MLP_GRID, 256, 0, stream>>>(zbuf, zbuf, mw1,        mb1,       mw2,        mb2,       stats + 0,   stats + 64);
  k_hfin<<<1, 64, 0, stream>>>(stats + 0, bng + 0, bnb + 0, ss, 1.f / N_NODES, 64);
  k_bnapply<<<APP_GRID, 256, 0, stream>>>(zbuf, hbuf, ss);
  // layer 1
  k_agg<<<AGG_GRID, 256, 0, stream>>>(hbuf, zbuf, offs, csr);
  k_mlp<<<MLP_GRID, 256, 0, stream>>>(zbuf, zbuf, mw1 + 4096, mb1 + 64,  mw2 + 4096, mb2 + 64,  stats + 128, stats + 192);
  k_hfin<<<1, 64, 0, stream>>>(stats + 128, bng + 64, bnb + 64, ss, 1.f / N_NODES, 64);
  k_bnapply<<<APP_GRID, 256, 0, stream>>>(zbuf, hbuf, ss);
  // layer 2
  k_agg<<<AGG_GRID, 256, 0, stream>>>(hbuf, zbuf, offs, csr);
  k_mlp<<<MLP_GRID, 256, 0, stream>>>(zbuf, zbuf, mw1 + 8192, mb1 + 128, mw2 + 8192, mb2 + 128, stats + 256, stats + 320);
  k_hfin<<<1, 64, 0, stream>>>(stats + 256, bng + 128, bnb + 128, ss, 1.f / N_NODES, 64);
  k_bnapply<<<APP_GRID, 256, 0, stream>>>(zbuf, hbuf, ss);

  k_pool<<<256, 256, 0, stream>>>(hbuf, btw, flag, gsum, gcnt);
  k_head1<<<NG / 4, 256, 0, stream>>>(gsum, gcnt, hw1, hb1, p1, stats + 384);
  k_hfin<<<1, 64, 0, stream>>>(stats + 384, hg1, hbb1, ss, 1.f / NG, 64);
  k_head2<<<NG / 4, 256, 0, stream>>>(p1, ss, hw2, hb2, p2, stats + 512);
  k_hfin<<<1, 64, 0, stream>>>(stats + 512, hg2, hbb2, ss2, 1.f / NG, 32);
  k_head3<<<NG / 4, 256, 0, stream>>>(p2, ss2, ow, ob, out);
}

// Round 6
// 638.805 us; speedup vs baseline: 2.1155x; 1.1646x over previous
//
#include <hip/hip_runtime.h>
#include <hip/hip_bf16.h>

#define N_NODES 100000
#define N_EDGES 1200000
#define NG 512

typedef float f32;
typedef unsigned short u16;
typedef unsigned short us8 __attribute__((ext_vector_type(8)));

__device__ __forceinline__ f32 bf2f(u16 v) {
  return __uint_as_float(((unsigned)v) << 16);
}
__device__ __forceinline__ u16 f2bf(f32 f) {
  __hip_bfloat16 b = __float2bfloat16(f);   // RNE
  return *reinterpret_cast<u16*>(&b);
}

// ---------------- dtype probe: int64 vs int32 edge/batch arrays ----------------
__global__ void k_detect(const int* __restrict__ w, int* __restrict__ flag) {
  int t = threadIdx.x;
  int acc = 0;
  #pragma unroll
  for (int k = 0; k < 8; ++k) acc |= w[(t * 8 + k) * 2 + 1];
  if (acc) atomicOr(flag, 1);
}

// ---------------- CSR build ----------------
__global__ void k_count(const int* __restrict__ w, const int* __restrict__ flag,
                        int* __restrict__ deg, int* __restrict__ rank) {
  int e = blockIdx.x * 256 + threadIdx.x;
  if (e >= N_EDGES) return;
  int d = flag[0] ? w[N_EDGES + e] : w[2 * (N_EDGES + e)];
  rank[e] = atomicAdd(&deg[d], 1);
}

__global__ void k_scan1(const int* __restrict__ deg, int* __restrict__ incl, int* __restrict__ bsums) {
  __shared__ int sd[256];
  int t = threadIdx.x, b = blockIdx.x;
  int base = b * 1024 + t * 4;
  int v0 = (base + 0 < N_NODES) ? deg[base + 0] : 0;
  int v1 = (base + 1 < N_NODES) ? deg[base + 1] : 0;
  int v2 = (base + 2 < N_NODES) ? deg[base + 2] : 0;
  int v3 = (base + 3 < N_NODES) ? deg[base + 3] : 0;
  int s = v0 + v1 + v2 + v3;
  sd[t] = s; __syncthreads();
  for (int off = 1; off < 256; off <<= 1) {
    int x = (t >= off) ? sd[t - off] : 0; __syncthreads();
    sd[t] += x; __syncthreads();
  }
  int run = sd[t] - s;
  run += v0; if (base + 0 < N_NODES) incl[base + 0] = run;
  run += v1; if (base + 1 < N_NODES) incl[base + 1] = run;
  run += v2; if (base + 2 < N_NODES) incl[base + 2] = run;
  run += v3; if (base + 3 < N_NODES) incl[base + 3] = run;
  if (t == 255) bsums[b] = sd[255];
}

__global__ void k_scan2(int* __restrict__ bsums, int nb) {
  __shared__ int sd[128];
  int t = threadIdx.x;
  int v = (t < nb) ? bsums[t] : 0;
  sd[t] = v; __syncthreads();
  for (int off = 1; off < 128; off <<= 1) {
    int x = (t >= off) ? sd[t - off] : 0; __syncthreads();
    sd[t] += x; __syncthreads();
  }
  if (t < nb) bsums[t] = sd[t] - v;
}

__global__ void k_scan3(const int* __restrict__ incl, const int* __restrict__ bsums,
                        int* __restrict__ offs) {
  int i = blockIdx.x * 256 + threadIdx.x;
  if (i >= N_NODES) return;
  int start = (i == 0) ? 0 : (incl[i - 1] + bsums[(i - 1) >> 10]);
  offs[i] = start;
  if (i == N_NODES - 1) offs[N_NODES] = incl[i] + bsums[i >> 10];
}

__global__ void k_fill(const int* __restrict__ w, const int* __restrict__ flag,
                       const int* __restrict__ offs, const int* __restrict__ rank,
                       int* __restrict__ csr) {
  int e = blockIdx.x * 256 + threadIdx.x;
  if (e >= N_EDGES) return;
  int is32 = flag[0];
  int s = is32 ? w[e] : w[2 * e];
  int d = is32 ? w[N_EDGES + e] : w[2 * (N_EDGES + e)];
  csr[offs[d] + rank[e]] = s;
}

// ---------------- cast x (f32) -> bf16 h ----------------
__global__ void k_cast(const f32* __restrict__ x, u16* __restrict__ h) {
  int i = blockIdx.x * 256 + threadIdx.x;   // 8 elems per thread
  if (i >= N_NODES * 8) return;
  float4 v0 = ((const float4*)x)[i * 2 + 0];
  float4 v1 = ((const float4*)x)[i * 2 + 1];
  us8 r;
  r[0] = f2bf(v0.x); r[1] = f2bf(v0.y); r[2] = f2bf(v0.z); r[3] = f2bf(v0.w);
  r[4] = f2bf(v1.x); r[5] = f2bf(v1.y); r[6] = f2bf(v1.z); r[7] = f2bf(v1.w);
  *(us8*)&h[i * 8] = r;
}

// ---------------- aggregation: wave/node, 8 edge-slots x 8 f-lanes, bf16 ------
__global__ __launch_bounds__(256) void k_agg(const u16* __restrict__ hin,
                                             f32* __restrict__ z,
                                             const int* __restrict__ offs,
                                             const int* __restrict__ csr) {
  int wid = blockIdx.x * 4 + (threadIdx.x >> 6);
  int lane = threadIdx.x & 63;
  int slot = lane >> 3;          // 0..7 edge slot
  int fl = (lane & 7) << 3;      // feature offset (8 bf16 = 16B)
  int e0 = offs[wid], e1 = offs[wid + 1];
  f32 a0[8] = {0,0,0,0,0,0,0,0};
  f32 a1[8] = {0,0,0,0,0,0,0,0};
  int e = e0 + slot;
  for (; e + 8 < e1; e += 16) {
    int s0 = csr[e], s1 = csr[e + 8];
    us8 v0 = *(const us8*)&hin[s0 * 64 + fl];
    us8 v1 = *(const us8*)&hin[s1 * 64 + fl];
    #pragma unroll
    for (int k = 0; k < 8; ++k) { a0[k] += bf2f(v0[k]); a1[k] += bf2f(v1[k]); }
  }
  if (e < e1) {
    us8 v0 = *(const us8*)&hin[csr[e] * 64 + fl];
    #pragma unroll
    for (int k = 0; k < 8; ++k) a0[k] += bf2f(v0[k]);
  }
  #pragma unroll
  for (int k = 0; k < 8; ++k) a0[k] += a1[k];
  #pragma unroll
  for (int k = 0; k < 8; ++k) {
    a0[k] += __shfl_xor(a0[k], 8);
    a0[k] += __shfl_xor(a0[k], 16);
    a0[k] += __shfl_xor(a0[k], 32);
  }
  if (slot == 0) {
    us8 sv = *(const us8*)&hin[wid * 64 + fl];
    float4 o0, o1;
    o0.x = a0[0] + bf2f(sv[0]); o0.y = a0[1] + bf2f(sv[1]);
    o0.z = a0[2] + bf2f(sv[2]); o0.w = a0[3] + bf2f(sv[3]);
    o1.x = a0[4] + bf2f(sv[4]); o1.y = a0[5] + bf2f(sv[5]);
    o1.z = a0[6] + bf2f(sv[6]); o1.w = a0[7] + bf2f(sv[7]);
    *(float4*)&z[wid * 64 + fl] = o0;
    *(float4*)&z[wid * 64 + fl + 4] = o1;
  }
}

// ---------------- MLP: 2 GEMMs + BN stats (64-row tiles, in-place z->y) -------
#define GEMM_STEP(Ws) { \
    float4 w0 = *(const float4*)&Ws[(f + 0) * 64 + c0]; \
    float4 w1 = *(const float4*)&Ws[(f + 1) * 64 + c0]; \
    float4 w2 = *(const float4*)&Ws[(f + 2) * 64 + c0]; \
    float4 w3 = *(const float4*)&Ws[(f + 3) * 64 + c0]; \
    _Pragma("unroll") \
    for (int i = 0; i < 4; ++i) { \
      float4 a = *(const float4*)&As[(r0 + i) * 68 + f]; \
      acc[i][0] = fmaf(a.x, w0.x, fmaf(a.y, w1.x, fmaf(a.z, w2.x, fmaf(a.w, w3.x, acc[i][0])))); \
      acc[i][1] = fmaf(a.x, w0.y, fmaf(a.y, w1.y, fmaf(a.z, w2.y, fmaf(a.w, w3.y, acc[i][1])))); \
      acc[i][2] = fmaf(a.x, w0.z, fmaf(a.y, w1.z, fmaf(a.z, w2.z, fmaf(a.w, w3.z, acc[i][2])))); \
      acc[i][3] = fmaf(a.x, w0.w, fmaf(a.y, w1.w, fmaf(a.z, w2.w, fmaf(a.w, w3.w, acc[i][3])))); \
    } \
  }

__global__ __launch_bounds__(256) void k_mlp(
    const f32* __restrict__ zin, f32* __restrict__ yout,
    const f32* __restrict__ W1, const f32* __restrict__ b1,
    const f32* __restrict__ W2, const f32* __restrict__ b2,
    f32* __restrict__ stsum, f32* __restrict__ stsq)
{
  __shared__ f32 As[64 * 68];
  __shared__ f32 W1s[4096];
  __shared__ f32 W2s[4096];
  __shared__ f32 b1s[64], b2s[64], blks[64], blkq[64];
  const int t = threadIdx.x;
  for (int i = t; i < 4096; i += 256) { W1s[i] = W1[i]; W2s[i] = W2[i]; }
  if (t < 64) { b1s[t] = b1[t]; b2s[t] = b2[t]; blks[t] = 0.f; blkq[t] = 0.f; }
  const int base = blockIdx.x * 64;
  #pragma unroll
  for (int p = 0; p < 4; ++p) {
    int elem = p * 1024 + t * 4;
    int row = elem >> 6, col = elem & 63;
    if (base + row < N_NODES)
      *(float4*)&As[row * 68 + col] = *(const float4*)&zin[base * 64 + elem];
  }
  __syncthreads();
  const int r0 = (t >> 4) * 4, c0 = (t & 15) * 4;
  f32 acc[4][4];
  #pragma unroll
  for (int i = 0; i < 4; ++i) { acc[i][0] = acc[i][1] = acc[i][2] = acc[i][3] = 0.f; }
  #pragma unroll 4
  for (int f = 0; f < 64; f += 4) GEMM_STEP(W1s)
  __syncthreads();
  #pragma unroll
  for (int i = 0; i < 4; ++i) {
    float4 v;
    v.x = fmaxf(acc[i][0] + b1s[c0 + 0], 0.f);
    v.y = fmaxf(acc[i][1] + b1s[c0 + 1], 0.f);
    v.z = fmaxf(acc[i][2] + b1s[c0 + 2], 0.f);
    v.w = fmaxf(acc[i][3] + b1s[c0 + 3], 0.f);
    *(float4*)&As[(r0 + i) * 68 + c0] = v;
  }
  __syncthreads();
  #pragma unroll
  for (int i = 0; i < 4; ++i) { acc[i][0] = acc[i][1] = acc[i][2] = acc[i][3] = 0.f; }
  #pragma unroll 4
  for (int f = 0; f < 64; f += 4) GEMM_STEP(W2s)
  f32 ps0 = 0, ps1 = 0, ps2 = 0, ps3 = 0, pq0 = 0, pq1 = 0, pq2 = 0, pq3 = 0;
  #pragma unroll
  for (int i = 0; i < 4; ++i) {
    int node = base + r0 + i;
    if (node < N_NODES) {                       // GUARD: last block rows 100000..100031
      f32 y0 = acc[i][0] + b2s[c0 + 0];
      f32 y1 = acc[i][1] + b2s[c0 + 1];
      f32 y2 = acc[i][2] + b2s[c0 + 2];
      f32 y3 = acc[i][3] + b2s[c0 + 3];
      float4 v = { y0, y1, y2, y3 };
      *(float4*)&yout[node * 64 + c0] = v;
      ps0 += y0; pq0 += y0 * y0;
      ps1 += y1; pq1 += y1 * y1;
      ps2 += y2; pq2 += y2 * y2;
      ps3 += y3; pq3 += y3 * y3;
    }
  }
  atomicAdd(&blks[c0 + 0], ps0); atomicAdd(&blkq[c0 + 0], pq0);
  atomicAdd(&blks[c0 + 1], ps1); atomicAdd(&blkq[c0 + 1], pq1);
  atomicAdd(&blks[c0 + 2], ps2); atomicAdd(&blkq[c0 + 2], pq2);
  atomicAdd(&blks[c0 + 3], ps3); atomicAdd(&blkq[c0 + 3], pq3);
  __syncthreads();
  if (t < 64) { atomicAdd(&stsum[t], blks[t]); atomicAdd(&stsq[t], blkq[t]); }
}

// ---------------- BN finalize ----------------
__global__ void k_hfin(const f32* __restrict__ st, const f32* __restrict__ g,
                       const f32* __restrict__ b, f32* __restrict__ ss, f32 invn, int d) {
  int t = threadIdx.x;
  if (t < d) {
    f32 m = st[t] * invn;
    f32 var = st[64 + t] * invn - m * m;
    f32 inv = rsqrtf(var + 1e-5f);
    f32 sc = g[t] * inv;
    ss[t] = sc;
    ss[64 + t] = b[t] - m * sc;
  }
}

// ---------------- BN apply + relu -> bf16 h ----------------
__global__ void k_bnapply(const f32* __restrict__ y, u16* __restrict__ h,
                          const f32* __restrict__ ss) {
  int i = blockIdx.x * 256 + threadIdx.x;   // 8 elems per thread
  if (i >= N_NODES * 8) return;
  int c0 = (i & 7) * 8;
  float4 v0 = ((const float4*)y)[i * 2 + 0];
  float4 v1 = ((const float4*)y)[i * 2 + 1];
  us8 r;
  r[0] = f2bf(fmaxf(fmaf(v0.x, ss[c0 + 0], ss[64 + c0 + 0]), 0.f));
  r[1] = f2bf(fmaxf(fmaf(v0.y, ss[c0 + 1], ss[64 + c0 + 1]), 0.f));
  r[2] = f2bf(fmaxf(fmaf(v0.z, ss[c0 + 2], ss[64 + c0 + 2]), 0.f));
  r[3] = f2bf(fmaxf(fmaf(v0.w, ss[c0 + 3], ss[64 + c0 + 3]), 0.f));
  r[4] = f2bf(fmaxf(fmaf(v1.x, ss[c0 + 4], ss[64 + c0 + 4]), 0.f));
  r[5] = f2bf(fmaxf(fmaf(v1.y, ss[c0 + 5], ss[64 + c0 + 5]), 0.f));
  r[6] = f2bf(fmaxf(fmaf(v1.z, ss[c0 + 6], ss[64 + c0 + 6]), 0.f));
  r[7] = f2bf(fmaxf(fmaf(v1.w, ss[c0 + 7], ss[64 + c0 + 7]), 0.f));
  *(us8*)&h[i * 8] = r;
}

// ---------------- global mean pool (batch sorted, bf16 h) ----------------
__global__ void k_pool(const u16* __restrict__ h, const int* __restrict__ bw,
                       const int* __restrict__ flag,
                       f32* __restrict__ gsum, f32* __restrict__ gcnt) {
  int wid = (blockIdx.x * blockDim.x + threadIdx.x) >> 6;
  int lane = threadIdx.x & 63;
  const int nw = (256 * 256) >> 6;
  const int per = (N_NODES + nw - 1) / nw;
  int s = wid * per; int e = s + per; if (e > N_NODES) e = N_NODES;
  if (s >= e) return;
  int is32 = flag[0];
  int g = is32 ? bw[s] : bw[2 * s];
  f32 acc = 0.f, cnt = 0.f;
  for (int i = s; i < e; ++i) {
    int gi = is32 ? bw[i] : bw[2 * i];
    if (gi != g) {
      atomicAdd(&gsum[g * 64 + lane], acc);
      if (lane == 0) atomicAdd(&gcnt[g], cnt);
      g = gi; acc = 0.f; cnt = 0.f;
    }
    acc += bf2f(h[i * 64 + lane]);
    cnt += 1.f;
  }
  atomicAdd(&gsum[g * 64 + lane], acc);
  if (lane == 0) atomicAdd(&gcnt[g], cnt);
}

// ---------------- head ----------------
__global__ __launch_bounds__(256) void k_head1(const f32* __restrict__ gsum, const f32* __restrict__ gcnt,
                                               const f32* __restrict__ W, const f32* __restrict__ bias,
                                               f32* __restrict__ p, f32* __restrict__ st) {
  __shared__ f32 Ws[4096];
  __shared__ f32 zs[4][64];
  __shared__ f32 bs[64], bq[64];
  int t = threadIdx.x;
  for (int i = t; i < 4096; i += 256) Ws[i] = W[i];
  if (t < 64) { bs[t] = 0.f; bq[t] = 0.f; }
  int wave = t >> 6, lane = t & 63;
  int row = blockIdx.x * 4 + wave;
  f32 z = gsum[row * 64 + lane] / fmaxf(gcnt[row], 1.f);
  zs[wave][lane] = z;
  __syncthreads();
  f32 y = bias[lane];
  for (int f = 0; f < 64; ++f) y = fmaf(zs[wave][f], Ws[f * 64 + lane], y);
  p[row * 64 + lane] = y;
  atomicAdd(&bs[lane], y);
  atomicAdd(&bq[lane], y * y);
  __syncthreads();
  if (t < 64) { atomicAdd(&st[t], bs[t]); atomicAdd(&st[64 + t], bq[t]); }
}

__global__ __launch_bounds__(256) void k_head2(const f32* __restrict__ p1, const f32* __restrict__ ss,
                                               const f32* __restrict__ W, const f32* __restrict__ bias,
                                               f32* __restrict__ p2, f32* __restrict__ st) {
  __shared__ f32 Ws[2048];
  __shared__ f32 zs[4][64];
  __shared__ f32 bs[32], bq[32];
  int t = threadIdx.x;
  for (int i = t; i < 2048; i += 256) Ws[i] = W[i];
  if (t < 32) { bs[t] = 0.f; bq[t] = 0.f; }
  int wave = t >> 6, lane = t & 63;
  int row = blockIdx.x * 4 + wave;
  f32 z = fmaxf(fmaf(p1[row * 64 + lane], ss[lane], ss[64 + lane]), 0.f);
  zs[wave][lane] = z;
  __syncthreads();
  if (lane < 32) {
    f32 y = bias[lane];
    for (int f = 0; f < 64; ++f) y = fmaf(zs[wave][f], Ws[f * 32 + lane], y);
    p2[row * 32 + lane] = y;
    atomicAdd(&bs[lane], y);
    atomicAdd(&bq[lane], y * y);
  }
  __syncthreads();
  if (t < 32) { atomicAdd(&st[t], bs[t]); atomicAdd(&st[64 + t], bq[t]); }
}

__global__ __launch_bounds__(256) void k_head3(const f32* __restrict__ p2, const f32* __restrict__ ss,
                                               const f32* __restrict__ W, const f32* __restrict__ bias,
                                               f32* __restrict__ out) {
  __shared__ f32 Ws[320];
  __shared__ f32 obs[10];
  __shared__ f32 zs[4][32];
  int t = threadIdx.x;
  for (int i = t; i < 320; i += 256) Ws[i] = W[i];
  if (t < 10) obs[t] = bias[t];
  int wave = t >> 6, lane = t & 63;
  int row = blockIdx.x * 4 + wave;
  if (lane < 32) zs[wave][lane] = fmaxf(fmaf(p2[row * 32 + lane], ss[lane], ss[64 + lane]), 0.f);
  __syncthreads();
  if (lane < 10) {
    f32 o = obs[lane];
    for (int f = 0; f < 32; ++f) o = fmaf(zs[wave][f], Ws[f * 10 + lane], o);
    out[row * 10 + lane] = o;
  }
}

extern "C" void kernel_launch(void* const* d_in, const int* in_sizes, int n_in,
                              void* d_out, int out_size, void* d_ws, size_t ws_size,
                              hipStream_t stream) {
  (void)in_sizes; (void)n_in; (void)out_size; (void)ws_size;
  const f32* x    = (const f32*)d_in[0];
  const int* eiw  = (const int*)d_in[1];
  const int* btw  = (const int*)d_in[2];
  const f32* mw1  = (const f32*)d_in[3];
  const f32* mb1  = (const f32*)d_in[4];
  const f32* mw2  = (const f32*)d_in[5];
  const f32* mb2  = (const f32*)d_in[6];
  const f32* bng  = (const f32*)d_in[7];
  const f32* bnb  = (const f32*)d_in[8];
  const f32* hw1  = (const f32*)d_in[9];
  const f32* hb1  = (const f32*)d_in[10];
  const f32* hg1  = (const f32*)d_in[11];
  const f32* hbb1 = (const f32*)d_in[12];
  const f32* hw2  = (const f32*)d_in[13];
  const f32* hb2  = (const f32*)d_in[14];
  const f32* hg2  = (const f32*)d_in[15];
  const f32* hbb2 = (const f32*)d_in[16];
  const f32* ow   = (const f32*)d_in[17];
  const f32* ob   = (const f32*)d_in[18];
  f32* out = (f32*)d_out;

  int* deg    = (int*)d_ws;           // 100000
  int* incl   = deg + N_NODES;        // 100000
  int* bsums  = incl + N_NODES;       // 128
  int* flag   = bsums + 128;          // 4
  int* offs   = flag + 4;             // 100004 (incl. pad)
  int* rank   = offs + 100004;        // 1200000
  int* csr    = rank + N_EDGES;       // 1200000
  u16* hbuf   = (u16*)(csr + N_EDGES);    // N_NODES*64 bf16 (16B-aligned)
  f32* zbuf   = (f32*)(hbuf + N_NODES * 64);
  f32* stats  = zbuf + N_NODES * 64;  // 1024
  f32* ss     = stats + 1024;         // 128
  f32* ss2    = ss + 128;             // 128
  f32* gsum   = ss2 + 128;            // NG*64
  f32* gcnt   = gsum + NG * 64;       // NG
  f32* p1     = gcnt + NG;            // NG*64
  f32* p2     = p1 + NG * 64;         // NG*32

  hipMemsetAsync(deg, 0, N_NODES * sizeof(int), stream);
  hipMemsetAsync(flag, 0, sizeof(int), stream);
  hipMemsetAsync(stats, 0, 1024 * sizeof(f32), stream);
  hipMemsetAsync(gsum, 0, (NG * 64 + NG) * sizeof(f32), stream);

  k_detect<<<1, 256, 0, stream>>>(eiw, flag);
  k_count<<<(N_EDGES + 255) / 256, 256, 0, stream>>>(eiw, flag, deg, rank);
  k_scan1<<<(N_NODES + 1023) / 1024, 256, 0, stream>>>(deg, incl, bsums);
  k_scan2<<<1, 128, 0, stream>>>(bsums, (N_NODES + 1023) / 1024);
  k_scan3<<<(N_NODES + 255) / 256, 256, 0, stream>>>(incl, bsums, offs);
  k_fill<<<(N_EDGES + 255) / 256, 256, 0, stream>>>(eiw, flag, offs, rank, csr);

  const int AGG_GRID = N_NODES / 4;              // 1 wave per node
  const int MLP_GRID = (N_NODES + 63) / 64;
  const int C8_GRID  = (N_NODES * 8 + 255) / 256;

  k_cast<<<C8_GRID, 256, 0, stream>>>(x, hbuf);
  // layer 0
  k_agg<<<AGG_GRID, 256, 0, stream>>>(hbuf, zbuf, offs, csr);
  k_mlp<<<MLP_GRID, 256, 0, stream>>>(zbuf, zbuf, mw1,        mb1,       mw2,        mb2,       stats + 0,   stats + 64);
  k_hfin<<<1, 64, 0, stream>>>(stats + 0, bng + 0, bnb + 0, ss, 1.f / N_NODES, 64);
  k_bnapply<<<C8_GRID, 256, 0, stream>>>(zbuf, hbuf, ss);
  // layer 1
  k_agg<<<AGG_GRID, 256, 0, stream>>>(hbuf, zbuf, offs, csr);
  k_mlp<<<MLP_GRID, 256, 0, stream>>>(zbuf, zbuf, mw1 + 4096, mb1 + 64,  mw2 + 4096, mb2 + 64,  stats + 128, stats + 192);
  k_hfin<<<1, 64, 0, stream>>>(stats + 128, bng + 64, bnb + 64, ss, 1.f / N_NODES, 64);
  k_bnapply<<<C8_GRID, 256, 0, stream>>>(zbuf, hbuf, ss);
  // layer 2
  k_agg<<<AGG_GRID, 256, 0, stream>>>(hbuf, zbuf, offs, csr);
  k_mlp<<<MLP_GRID, 256, 0, stream>>>(zbuf, zbuf, mw1 + 8192, mb1 + 128, mw2 + 8192, mb2 + 128, stats + 256, stats + 320);
  k_hfin<<<1, 64, 0, stream>>>(stats + 256, bng + 128, bnb + 128, ss, 1.f / N_NODES, 64);
  k_bnapply<<<C8_GRID, 256, 0, stream>>>(zbuf, hbuf, ss);

  k_pool<<<256, 256, 0, stream>>>(hbuf, btw, flag, gsum, gcnt);
  k_head1<<<NG / 4, 256, 0, stream>>>(gsum, gcnt, hw1, hb1, p1, stats + 384);
  k_hfin<<<1, 64, 0, stream>>>(stats + 384, hg1, hbb1, ss, 1.f / NG, 64);
  k_head2<<<NG / 4, 256, 0, stream>>>(p1, ss, hw2, hb2, p2, stats + 512);
  k_hfin<<<1, 64, 0, stream>>>(stats + 512, hg2, hbb2, ss2, 1.f / NG, 32);
  k_head3<<<NG / 4, 256, 0, stream>>>(p2, ss2, ow, ob, out);
}

// Round 7
// 521.796 us; speedup vs baseline: 2.5899x; 1.2242x over previous
//
#include <hip/hip_runtime.h>
#include <hip/hip_bf16.h>

#define N_NODES 100000
#define N_EDGES 1200000
#define NG 512

typedef float f32;
typedef unsigned short u16;
typedef unsigned short us8 __attribute__((ext_vector_type(8)));
typedef __bf16 bf16x8 __attribute__((ext_vector_type(8)));
typedef float f32x16 __attribute__((ext_vector_type(16)));

__device__ __forceinline__ f32 bf2f(u16 v) {
  return __uint_as_float(((unsigned)v) << 16);
}
__device__ __forceinline__ u16 f2bf(f32 f) {
  __hip_bfloat16 b = __float2bfloat16(f);   // RNE
  return *reinterpret_cast<u16*>(&b);
}

// ---------------- dtype probe: int64 vs int32 edge/batch arrays ----------------
__global__ void k_detect(const int* __restrict__ w, int* __restrict__ flag) {
  int t = threadIdx.x;
  int acc = 0;
  #pragma unroll
  for (int k = 0; k < 8; ++k) acc |= w[(t * 8 + k) * 2 + 1];
  if (acc) atomicOr(flag, 1);
}

// ---------------- CSR build ----------------
__global__ void k_count(const int* __restrict__ w, const int* __restrict__ flag,
                        int* __restrict__ deg, int* __restrict__ rank) {
  int e = blockIdx.x * 256 + threadIdx.x;
  if (e >= N_EDGES) return;
  int d = flag[0] ? w[N_EDGES + e] : w[2 * (N_EDGES + e)];
  rank[e] = atomicAdd(&deg[d], 1);
}

__global__ void k_scan1(const int* __restrict__ deg, int* __restrict__ incl, int* __restrict__ bsums) {
  __shared__ int sd[256];
  int t = threadIdx.x, b = blockIdx.x;
  int base = b * 1024 + t * 4;
  int v0 = (base + 0 < N_NODES) ? deg[base + 0] : 0;
  int v1 = (base + 1 < N_NODES) ? deg[base + 1] : 0;
  int v2 = (base + 2 < N_NODES) ? deg[base + 2] : 0;
  int v3 = (base + 3 < N_NODES) ? deg[base + 3] : 0;
  int s = v0 + v1 + v2 + v3;
  sd[t] = s; __syncthreads();
  for (int off = 1; off < 256; off <<= 1) {
    int x = (t >= off) ? sd[t - off] : 0; __syncthreads();
    sd[t] += x; __syncthreads();
  }
  int run = sd[t] - s;
  run += v0; if (base + 0 < N_NODES) incl[base + 0] = run;
  run += v1; if (base + 1 < N_NODES) incl[base + 1] = run;
  run += v2; if (base + 2 < N_NODES) incl[base + 2] = run;
  run += v3; if (base + 3 < N_NODES) incl[base + 3] = run;
  if (t == 255) bsums[b] = sd[255];
}

__global__ void k_scan2(int* __restrict__ bsums, int nb) {
  __shared__ int sd[128];
  int t = threadIdx.x;
  int v = (t < nb) ? bsums[t] : 0;
  sd[t] = v; __syncthreads();
  for (int off = 1; off < 128; off <<= 1) {
    int x = (t >= off) ? sd[t - off] : 0; __syncthreads();
    sd[t] += x; __syncthreads();
  }
  if (t < nb) bsums[t] = sd[t] - v;
}

__global__ void k_scan3(const int* __restrict__ incl, const int* __restrict__ bsums,
                        int* __restrict__ offs) {
  int i = blockIdx.x * 256 + threadIdx.x;
  if (i >= N_NODES) return;
  int start = (i == 0) ? 0 : (incl[i - 1] + bsums[(i - 1) >> 10]);
  offs[i] = start;
  if (i == N_NODES - 1) offs[N_NODES] = incl[i] + bsums[i >> 10];
}

__global__ void k_fill(const int* __restrict__ w, const int* __restrict__ flag,
                       const int* __restrict__ offs, const int* __restrict__ rank,
                       int* __restrict__ csr) {
  int e = blockIdx.x * 256 + threadIdx.x;
  if (e >= N_EDGES) return;
  int is32 = flag[0];
  int s = is32 ? w[e] : w[2 * e];
  int d = is32 ? w[N_EDGES + e] : w[2 * (N_EDGES + e)];
  csr[offs[d] + rank[e]] = s;
}

// ---------------- cast x (f32) -> bf16 h ----------------
__global__ void k_cast(const f32* __restrict__ x, u16* __restrict__ h) {
  int i = blockIdx.x * 256 + threadIdx.x;   // 8 elems per thread
  if (i >= N_NODES * 8) return;
  float4 v0 = ((const float4*)x)[i * 2 + 0];
  float4 v1 = ((const float4*)x)[i * 2 + 1];
  us8 r;
  r[0] = f2bf(v0.x); r[1] = f2bf(v0.y); r[2] = f2bf(v0.z); r[3] = f2bf(v0.w);
  r[4] = f2bf(v1.x); r[5] = f2bf(v1.y); r[6] = f2bf(v1.z); r[7] = f2bf(v1.w);
  *(us8*)&h[i * 8] = r;
}

// ---------------- aggregation: wave/node, 8 edge-slots x 8 f-lanes, bf16 ------
// writes z as bf16 now
__global__ __launch_bounds__(256) void k_agg(const u16* __restrict__ hin,
                                             u16* __restrict__ z,
                                             const int* __restrict__ offs,
                                             const int* __restrict__ csr) {
  int wid = blockIdx.x * 4 + (threadIdx.x >> 6);
  int lane = threadIdx.x & 63;
  int slot = lane >> 3;          // 0..7 edge slot
  int fl = (lane & 7) << 3;      // feature offset (8 bf16 = 16B)
  int e0 = offs[wid], e1 = offs[wid + 1];
  f32 a0[8] = {0,0,0,0,0,0,0,0};
  f32 a1[8] = {0,0,0,0,0,0,0,0};
  int e = e0 + slot;
  for (; e + 8 < e1; e += 16) {
    int s0 = csr[e], s1 = csr[e + 8];
    us8 v0 = *(const us8*)&hin[s0 * 64 + fl];
    us8 v1 = *(const us8*)&hin[s1 * 64 + fl];
    #pragma unroll
    for (int k = 0; k < 8; ++k) { a0[k] += bf2f(v0[k]); a1[k] += bf2f(v1[k]); }
  }
  if (e < e1) {
    us8 v0 = *(const us8*)&hin[csr[e] * 64 + fl];
    #pragma unroll
    for (int k = 0; k < 8; ++k) a0[k] += bf2f(v0[k]);
  }
  #pragma unroll
  for (int k = 0; k < 8; ++k) a0[k] += a1[k];
  #pragma unroll
  for (int k = 0; k < 8; ++k) {
    a0[k] += __shfl_xor(a0[k], 8);
    a0[k] += __shfl_xor(a0[k], 16);
    a0[k] += __shfl_xor(a0[k], 32);
  }
  if (slot == 0) {
    us8 sv = *(const us8*)&hin[wid * 64 + fl];
    us8 o;
    #pragma unroll
    for (int k = 0; k < 8; ++k) o[k] = f2bf(a0[k] + bf2f(sv[k]));
    *(us8*)&z[wid * 64 + fl] = o;
  }
}

// ---------------- MFMA MLP: 2 bf16 GEMMs + BN stats, 128-row tile/block -------
// LDS rows are 128B -> XOR-swizzle byte ^= (row&7)<<4 on both write and read.
__global__ __launch_bounds__(256) void k_mlp(
    const u16* __restrict__ zin, f32* __restrict__ yout,
    const f32* __restrict__ W1, const f32* __restrict__ b1,
    const f32* __restrict__ W2, const f32* __restrict__ b2,
    f32* __restrict__ stsum, f32* __restrict__ stsq)
{
  __shared__ __align__(16) u16 zs[128 * 64];      // 16KB bf16 z tile
  __shared__ __align__(16) u16 wt1[64 * 64];      // 8KB Wt1[c][k]
  __shared__ __align__(16) u16 wt2[64 * 64];      // 8KB Wt2[c][k]
  __shared__ __align__(16) u16 mid[4 * 32 * 64];  // 16KB, per-wave [32][64]
  __shared__ f32 b1s[64], b2s[64], blks[64], blkq[64];
  const int t = threadIdx.x;
  char* zb = (char*)zs; char* w1b = (char*)wt1; char* w2b = (char*)wt2; char* mb = (char*)mid;
  const int base = blockIdx.x * 128;
  // stage z tile (rows base..base+127; zin padded to 100096 rows)
  #pragma unroll
  for (int r = 0; r < 4; ++r) {
    int off = r * 4096 + t * 16;
    int row = off >> 7, c = off & 127;
    *(us8*)(zb + row * 128 + (c ^ ((row & 7) << 4))) =
        *(const us8*)((const char*)(zin + (size_t)base * 64) + off);
  }
  // stage transposed bf16 weights: Wt[c][k] <- W[k][c]
  #pragma unroll
  for (int i0 = 0; i0 < 16; ++i0) {
    int i = i0 * 256 + t;
    int k = i >> 6, c = i & 63;
    int off = c * 128 + ((k * 2) ^ ((c & 7) << 4));
    *(u16*)(w1b + off) = f2bf(W1[i]);
    *(u16*)(w2b + off) = f2bf(W2[i]);
  }
  if (t < 64) { b1s[t] = b1[t]; b2s[t] = b2[t]; blks[t] = 0.f; blkq[t] = 0.f; }
  __syncthreads();
  const int wv = t >> 6, l = t & 63;
  const int lr = l & 31, lh = l >> 5;
  // ---- GEMM1: C = z @ W1 (rows wv*32..+31, cols 0..63)
  f32x16 acc0, acc1;
  #pragma unroll
  for (int i = 0; i < 16; ++i) { acc0[i] = 0.f; acc1[i] = 0.f; }
  #pragma unroll
  for (int s = 0; s < 4; ++s) {
    int kb = s * 32 + lh * 16;                 // byte offset of 8-elem k-chunk
    int arow = wv * 32 + lr;
    bf16x8 a  = *(bf16x8*)(zb + arow * 128 + (kb ^ ((arow & 7) << 4)));
    bf16x8 bA = *(bf16x8*)(w1b + lr * 128 + (kb ^ ((lr & 7) << 4)));
    bf16x8 bB = *(bf16x8*)(w1b + (lr + 32) * 128 + (kb ^ (((lr + 32) & 7) << 4)));
    acc0 = __builtin_amdgcn_mfma_f32_32x32x16_bf16(a, bA, acc0, 0, 0, 0);
    acc1 = __builtin_amdgcn_mfma_f32_32x32x16_bf16(a, bB, acc1, 0, 0, 0);
  }
  // ---- epilogue1: relu(acc + b1) -> mid (wave-private tile)
  #pragma unroll
  for (int g = 0; g < 16; ++g) {
    int rowl = (g & 3) + 8 * (g >> 2) + 4 * lh;
    int roff = wv * 4096 + rowl * 128;
    int sw = (rowl & 7) << 4;
    *(u16*)(mb + roff + ((lr * 2) ^ sw))        = f2bf(fmaxf(acc0[g] + b1s[lr], 0.f));
    *(u16*)(mb + roff + (((lr + 32) * 2) ^ sw)) = f2bf(fmaxf(acc1[g] + b1s[lr + 32], 0.f));
  }
  asm volatile("s_waitcnt lgkmcnt(0)" ::: "memory");  // wave-local LDS visibility
  // ---- GEMM2: y = mid @ W2
  #pragma unroll
  for (int i = 0; i < 16; ++i) { acc0[i] = 0.f; acc1[i] = 0.f; }
  #pragma unroll
  for (int s = 0; s < 4; ++s) {
    int kb = s * 32 + lh * 16;
    bf16x8 a  = *(bf16x8*)(mb + wv * 4096 + lr * 128 + (kb ^ ((lr & 7) << 4)));
    bf16x8 bA = *(bf16x8*)(w2b + lr * 128 + (kb ^ ((lr & 7) << 4)));
    bf16x8 bB = *(bf16x8*)(w2b + (lr + 32) * 128 + (kb ^ (((lr + 32) & 7) << 4)));
    acc0 = __builtin_amdgcn_mfma_f32_32x32x16_bf16(a, bA, acc0, 0, 0, 0);
    acc1 = __builtin_amdgcn_mfma_f32_32x32x16_bf16(a, bB, acc1, 0, 0, 0);
  }
  // ---- epilogue2: y + b2, store f32, BN partial stats (guarded)
  f32 ps0 = 0, pq0 = 0, ps1 = 0, pq1 = 0;
  #pragma unroll
  for (int g = 0; g < 16; ++g) {
    int rowl = (g & 3) + 8 * (g >> 2) + 4 * lh;
    int node = base + wv * 32 + rowl;
    if (node < N_NODES) {
      f32 y0 = acc0[g] + b2s[lr];
      f32 y1 = acc1[g] + b2s[lr + 32];
      yout[(size_t)node * 64 + lr] = y0;
      yout[(size_t)node * 64 + lr + 32] = y1;
      ps0 += y0; pq0 += y0 * y0;
      ps1 += y1; pq1 += y1 * y1;
    }
  }
  atomicAdd(&blks[lr], ps0);      atomicAdd(&blkq[lr], pq0);
  atomicAdd(&blks[lr + 32], ps1); atomicAdd(&blkq[lr + 32], pq1);
  __syncthreads();
  if (t < 64) { atomicAdd(&stsum[t], blks[t]); atomicAdd(&stsq[t], blkq[t]); }
}

// ---------------- BN finalize ----------------
__global__ void k_hfin(const f32* __restrict__ st, const f32* __restrict__ g,
                       const f32* __restrict__ b, f32* __restrict__ ss, f32 invn, int d) {
  int t = threadIdx.x;
  if (t < d) {
    f32 m = st[t] * invn;
    f32 var = st[64 + t] * invn - m * m;
    f32 inv = rsqrtf(var + 1e-5f);
    f32 sc = g[t] * inv;
    ss[t] = sc;
    ss[64 + t] = b[t] - m * sc;
  }
}

// ---------------- BN apply + relu -> bf16 h ----------------
__global__ void k_bnapply(const f32* __restrict__ y, u16* __restrict__ h,
                          const f32* __restrict__ ss) {
  int i = blockIdx.x * 256 + threadIdx.x;   // 8 elems per thread
  if (i >= N_NODES * 8) return;
  int c0 = (i & 7) * 8;
  float4 v0 = ((const float4*)y)[i * 2 + 0];
  float4 v1 = ((const float4*)y)[i * 2 + 1];
  us8 r;
  r[0] = f2bf(fmaxf(fmaf(v0.x, ss[c0 + 0], ss[64 + c0 + 0]), 0.f));
  r[1] = f2bf(fmaxf(fmaf(v0.y, ss[c0 + 1], ss[64 + c0 + 1]), 0.f));
  r[2] = f2bf(fmaxf(fmaf(v0.z, ss[c0 + 2], ss[64 + c0 + 2]), 0.f));
  r[3] = f2bf(fmaxf(fmaf(v0.w, ss[c0 + 3], ss[64 + c0 + 3]), 0.f));
  r[4] = f2bf(fmaxf(fmaf(v1.x, ss[c0 + 4], ss[64 + c0 + 4]), 0.f));
  r[5] = f2bf(fmaxf(fmaf(v1.y, ss[c0 + 5], ss[64 + c0 + 5]), 0.f));
  r[6] = f2bf(fmaxf(fmaf(v1.z, ss[c0 + 6], ss[64 + c0 + 6]), 0.f));
  r[7] = f2bf(fmaxf(fmaf(v1.w, ss[c0 + 7], ss[64 + c0 + 7]), 0.f));
  *(us8*)&h[i * 8] = r;
}

// ---------------- global mean pool (batch sorted, bf16 h) ----------------
__global__ void k_pool(const u16* __restrict__ h, const int* __restrict__ bw,
                       const int* __restrict__ flag,
                       f32* __restrict__ gsum, f32* __restrict__ gcnt) {
  int wid = (blockIdx.x * blockDim.x + threadIdx.x) >> 6;
  int lane = threadIdx.x & 63;
  const int nw = (256 * 256) >> 6;
  const int per = (N_NODES + nw - 1) / nw;
  int s = wid * per; int e = s + per; if (e > N_NODES) e = N_NODES;
  if (s >= e) return;
  int is32 = flag[0];
  int g = is32 ? bw[s] : bw[2 * s];
  f32 acc = 0.f, cnt = 0.f;
  for (int i = s; i < e; ++i) {
    int gi = is32 ? bw[i] : bw[2 * i];
    if (gi != g) {
      atomicAdd(&gsum[g * 64 + lane], acc);
      if (lane == 0) atomicAdd(&gcnt[g], cnt);
      g = gi; acc = 0.f; cnt = 0.f;
    }
    acc += bf2f(h[i * 64 + lane]);
    cnt += 1.f;
  }
  atomicAdd(&gsum[g * 64 + lane], acc);
  if (lane == 0) atomicAdd(&gcnt[g], cnt);
}

// ---------------- head ----------------
__global__ __launch_bounds__(256) void k_head1(const f32* __restrict__ gsum, const f32* __restrict__ gcnt,
                                               const f32* __restrict__ W, const f32* __restrict__ bias,
                                               f32* __restrict__ p, f32* __restrict__ st) {
  __shared__ f32 Ws[4096];
  __shared__ f32 zs[4][64];
  __shared__ f32 bs[64], bq[64];
  int t = threadIdx.x;
  for (int i = t; i < 4096; i += 256) Ws[i] = W[i];
  if (t < 64) { bs[t] = 0.f; bq[t] = 0.f; }
  int wave = t >> 6, lane = t & 63;
  int row = blockIdx.x * 4 + wave;
  f32 z = gsum[row * 64 + lane] / fmaxf(gcnt[row], 1.f);
  zs[wave][lane] = z;
  __syncthreads();
  f32 y = bias[lane];
  for (int f = 0; f < 64; ++f) y = fmaf(zs[wave][f], Ws[f * 64 + lane], y);
  p[row * 64 + lane] = y;
  atomicAdd(&bs[lane], y);
  atomicAdd(&bq[lane], y * y);
  __syncthreads();
  if (t < 64) { atomicAdd(&st[t], bs[t]); atomicAdd(&st[64 + t], bq[t]); }
}

__global__ __launch_bounds__(256) void k_head2(const f32* __restrict__ p1, const f32* __restrict__ ss,
                                               const f32* __restrict__ W, const f32* __restrict__ bias,
                                               f32* __restrict__ p2, f32* __restrict__ st) {
  __shared__ f32 Ws[2048];
  __shared__ f32 zs[4][64];
  __shared__ f32 bs[32], bq[32];
  int t = threadIdx.x;
  for (int i = t; i < 2048; i += 256) Ws[i] = W[i];
  if (t < 32) { bs[t] = 0.f; bq[t] = 0.f; }
  int wave = t >> 6, lane = t & 63;
  int row = blockIdx.x * 4 + wave;
  f32 z = fmaxf(fmaf(p1[row * 64 + lane], ss[lane], ss[64 + lane]), 0.f);
  zs[wave][lane] = z;
  __syncthreads();
  if (lane < 32) {
    f32 y = bias[lane];
    for (int f = 0; f < 64; ++f) y = fmaf(zs[wave][f], Ws[f * 32 + lane], y);
    p2[row * 32 + lane] = y;
    atomicAdd(&bs[lane], y);
    atomicAdd(&bq[lane], y * y);
  }
  __syncthreads();
  if (t < 32) { atomicAdd(&st[t], bs[t]); atomicAdd(&st[64 + t], bq[t]); }
}

__global__ __launch_bounds__(256) void k_head3(const f32* __restrict__ p2, const f32* __restrict__ ss,
                                               const f32* __restrict__ W, const f32* __restrict__ bias,
                                               f32* __restrict__ out) {
  __shared__ f32 Ws[320];
  __shared__ f32 obs[10];
  __shared__ f32 zs[4][32];
  int t = threadIdx.x;
  for (int i = t; i < 320; i += 256) Ws[i] = W[i];
  if (t < 10) obs[t] = bias[t];
  int wave = t >> 6, lane = t & 63;
  int row = blockIdx.x * 4 + wave;
  if (lane < 32) zs[wave][lane] = fmaxf(fmaf(p2[row * 32 + lane], ss[lane], ss[64 + lane]), 0.f);
  __syncthreads();
  if (lane < 10) {
    f32 o = obs[lane];
    for (int f = 0; f < 32; ++f) o = fmaf(zs[wave][f], Ws[f * 10 + lane], o);
    out[row * 10 + lane] = o;
  }
}

extern "C" void kernel_launch(void* const* d_in, const int* in_sizes, int n_in,
                              void* d_out, int out_size, void* d_ws, size_t ws_size,
                              hipStream_t stream) {
  (void)in_sizes; (void)n_in; (void)out_size; (void)ws_size;
  const f32* x    = (const f32*)d_in[0];
  const int* eiw  = (const int*)d_in[1];
  const int* btw  = (const int*)d_in[2];
  const f32* mw1  = (const f32*)d_in[3];
  const f32* mb1  = (const f32*)d_in[4];
  const f32* mw2  = (const f32*)d_in[5];
  const f32* mb2  = (const f32*)d_in[6];
  const f32* bng  = (const f32*)d_in[7];
  const f32* bnb  = (const f32*)d_in[8];
  const f32* hw1  = (const f32*)d_in[9];
  const f32* hb1  = (const f32*)d_in[10];
  const f32* hg1  = (const f32*)d_in[11];
  const f32* hbb1 = (const f32*)d_in[12];
  const f32* hw2  = (const f32*)d_in[13];
  const f32* hb2  = (const f32*)d_in[14];
  const f32* hg2  = (const f32*)d_in[15];
  const f32* hbb2 = (const f32*)d_in[16];
  const f32* ow   = (const f32*)d_in[17];
  const f32* ob   = (const f32*)d_in[18];
  f32* out = (f32*)d_out;

  int* deg    = (int*)d_ws;           // 100000
  int* incl   = deg + N_NODES;        // 100000
  int* bsums  = incl + N_NODES;       // 128
  int* flag   = bsums + 128;          // 4
  int* offs   = flag + 4;             // 100004 (incl. pad)
  int* rank   = offs + 100004;        // 1200000
  int* csr    = rank + N_EDGES;       // 1200000
  u16* hbuf   = (u16*)(csr + N_EDGES);        // N_NODES*64 bf16
  u16* zbuf   = hbuf + (size_t)N_NODES * 64;  // 100096*64 bf16 (padded for 128-row tiles)
  f32* ybuf   = (f32*)(zbuf + (size_t)100096 * 64);
  f32* stats  = ybuf + (size_t)N_NODES * 64;  // 1024
  f32* ss     = stats + 1024;         // 128
  f32* ss2    = ss + 128;             // 128
  f32* gsum   = ss2 + 128;            // NG*64
  f32* gcnt   = gsum + NG * 64;       // NG
  f32* p1     = gcnt + NG;            // NG*64
  f32* p2     = p1 + NG * 64;         // NG*32

  hipMemsetAsync(deg, 0, N_NODES * sizeof(int), stream);
  hipMemsetAsync(flag, 0, sizeof(int), stream);
  hipMemsetAsync(stats, 0, 1024 * sizeof(f32), stream);
  hipMemsetAsync(gsum, 0, (NG * 64 + NG) * sizeof(f32), stream);

  k_detect<<<1, 256, 0, stream>>>(eiw, flag);
  k_count<<<(N_EDGES + 255) / 256, 256, 0, stream>>>(eiw, flag, deg, rank);
  k_scan1<<<(N_NODES + 1023) / 1024, 256, 0, stream>>>(deg, incl, bsums);
  k_scan2<<<1, 128, 0, stream>>>(bsums, (N_NODES + 1023) / 1024);
  k_scan3<<<(N_NODES + 255) / 256, 256, 0, stream>>>(incl, bsums, offs);
  k_fill<<<(N_EDGES + 255) / 256, 256, 0, stream>>>(eiw, flag, offs, rank, csr);

  const int AGG_GRID = N_NODES / 4;              // 1 wave per node
  const int MLP_GRID = (N_NODES + 127) / 128;    // 782, 128 rows per block
  const int C8_GRID  = (N_NODES * 8 + 255) / 256;

  k_cast<<<C8_GRID, 256, 0, stream>>>(x, hbuf);
  // layer 0
  k_agg<<<AGG_GRID, 256, 0, stream>>>(hbuf, zbuf, offs, csr);
  k_mlp<<<MLP_GRID, 256, 0, stream>>>(zbuf, ybuf, mw1,        mb1,       mw2,        mb2,       stats + 0,   stats + 64);
  k_hfin<<<1, 64, 0, stream>>>(stats + 0, bng + 0, bnb + 0, ss, 1.f / N_NODES, 64);
  k_bnapply<<<C8_GRID, 256, 0, stream>>>(ybuf, hbuf, ss);
  // layer 1
  k_agg<<<AGG_GRID, 256, 0, stream>>>(hbuf, zbuf, offs, csr);
  k_mlp<<<MLP_GRID, 256, 0, stream>>>(zbuf, ybuf, mw1 + 4096, mb1 + 64,  mw2 + 4096, mb2 + 64,  stats + 128, stats + 192);
  k_hfin<<<1, 64, 0, stream>>>(stats + 128, bng + 64, bnb + 64, ss, 1.f / N_NODES, 64);
  k_bnapply<<<C8_GRID, 256, 0, stream>>>(ybuf, hbuf, ss);
  // layer 2
  k_agg<<<AGG_GRID, 256, 0, stream>>>(hbuf, zbuf, offs, csr);
  k_mlp<<<MLP_GRID, 256, 0, stream>>>(zbuf, ybuf, mw1 + 8192, mb1 + 128, mw2 + 8192, mb2 + 128, stats + 256, stats + 320);
  k_hfin<<<1, 64, 0, stream>>>(stats + 256, bng + 128, bnb + 128, ss, 1.f / N_NODES, 64);
  k_bnapply<<<C8_GRID, 256, 0, stream>>>(ybuf, hbuf, ss);

  k_pool<<<256, 256, 0, stream>>>(hbuf, btw, flag, gsum, gcnt);
  k_head1<<<NG / 4, 256, 0, stream>>>(gsum, gcnt, hw1, hb1, p1, stats + 384);
  k_hfin<<<1, 64, 0, stream>>>(stats + 384, hg1, hbb1, ss, 1.f / NG, 64);
  k_head2<<<NG / 4, 256, 0, stream>>>(p1, ss, hw2, hb2, p2, stats + 512);
  k_hfin<<<1, 64, 0, stream>>>(stats + 512, hg2, hbb2, ss2, 1.f / NG, 32);
  k_head3<<<NG / 4, 256, 0, stream>>>(p2, ss2, ow, ob, out);
}

// Round 8
// 486.213 us; speedup vs baseline: 2.7794x; 1.0732x over previous
//
#include <hip/hip_runtime.h>
#include <hip/hip_bf16.h>

#define N_NODES 100000
#define N_EDGES 1200000
#define NG 512

typedef float f32;
typedef unsigned short u16;
typedef unsigned short us8 __attribute__((ext_vector_type(8)));
typedef __bf16 bf16x8 __attribute__((ext_vector_type(8)));
typedef float f32x16 __attribute__((ext_vector_type(16)));

__device__ __forceinline__ f32 bf2f(u16 v) {
  return __uint_as_float(((unsigned)v) << 16);
}
__device__ __forceinline__ u16 f2bf(f32 f) {
  __hip_bfloat16 b = __float2bfloat16(f);   // RNE
  return *reinterpret_cast<u16*>(&b);
}

// ---------------- dtype probe: int64 vs int32 ----------------
__global__ void k_detect(const int* __restrict__ w, int* __restrict__ flag) {
  int t = threadIdx.x;
  int acc = 0;
  #pragma unroll
  for (int k = 0; k < 8; ++k) acc |= w[(t * 8 + k) * 2 + 1];
  if (acc) atomicOr(flag, 1);
}

// ---------------- CSR build (2 edges/thread, vectorized reads) ----------------
__global__ void k_count(const int* __restrict__ w, const int* __restrict__ flag,
                        int* __restrict__ deg, int* __restrict__ rank) {
  int e2 = blockIdx.x * 256 + threadIdx.x;
  if (e2 >= N_EDGES / 2) return;
  int d0, d1;
  if (flag[0]) {
    int2 dd = *(const int2*)&w[N_EDGES + 2 * e2];
    d0 = dd.x; d1 = dd.y;
  } else {
    int4 dd = *(const int4*)&w[2 * N_EDGES + 4 * e2];
    d0 = dd.x; d1 = dd.z;
  }
  int2 rk;
  rk.x = atomicAdd(&deg[d0], 1);
  rk.y = atomicAdd(&deg[d1], 1);
  *(int2*)&rank[2 * e2] = rk;
}

__global__ void k_scan1(const int* __restrict__ deg, int* __restrict__ incl, int* __restrict__ bsums) {
  __shared__ int sd[256];
  int t = threadIdx.x, b = blockIdx.x;
  int base = b * 1024 + t * 4;
  int v0 = (base + 0 < N_NODES) ? deg[base + 0] : 0;
  int v1 = (base + 1 < N_NODES) ? deg[base + 1] : 0;
  int v2 = (base + 2 < N_NODES) ? deg[base + 2] : 0;
  int v3 = (base + 3 < N_NODES) ? deg[base + 3] : 0;
  int s = v0 + v1 + v2 + v3;
  sd[t] = s; __syncthreads();
  for (int off = 1; off < 256; off <<= 1) {
    int x = (t >= off) ? sd[t - off] : 0; __syncthreads();
    sd[t] += x; __syncthreads();
  }
  int run = sd[t] - s;
  run += v0; if (base + 0 < N_NODES) incl[base + 0] = run;
  run += v1; if (base + 1 < N_NODES) incl[base + 1] = run;
  run += v2; if (base + 2 < N_NODES) incl[base + 2] = run;
  run += v3; if (base + 3 < N_NODES) incl[base + 3] = run;
  if (t == 255) bsums[b] = sd[255];
}

__global__ void k_scan2(int* __restrict__ bsums, int nb) {
  __shared__ int sd[128];
  int t = threadIdx.x;
  int v = (t < nb) ? bsums[t] : 0;
  sd[t] = v; __syncthreads();
  for (int off = 1; off < 128; off <<= 1) {
    int x = (t >= off) ? sd[t - off] : 0; __syncthreads();
    sd[t] += x; __syncthreads();
  }
  if (t < nb) bsums[t] = sd[t] - v;
}

__global__ void k_scan3(const int* __restrict__ incl, const int* __restrict__ bsums,
                        int* __restrict__ offs) {
  int i = blockIdx.x * 256 + threadIdx.x;
  if (i >= N_NODES) return;
  int start = (i == 0) ? 0 : (incl[i - 1] + bsums[(i - 1) >> 10]);
  offs[i] = start;
  if (i == N_NODES - 1) offs[N_NODES] = incl[i] + bsums[i >> 10];
}

__global__ void k_fill(const int* __restrict__ w, const int* __restrict__ flag,
                       const int* __restrict__ offs, const int* __restrict__ rank,
                       int* __restrict__ csr) {
  int e2 = blockIdx.x * 256 + threadIdx.x;
  if (e2 >= N_EDGES / 2) return;
  int s0, s1, d0, d1;
  if (flag[0]) {
    int2 sv = *(const int2*)&w[2 * e2];
    int2 dv = *(const int2*)&w[N_EDGES + 2 * e2];
    s0 = sv.x; s1 = sv.y; d0 = dv.x; d1 = dv.y;
  } else {
    int4 sv = *(const int4*)&w[4 * e2];
    int4 dv = *(const int4*)&w[2 * N_EDGES + 4 * e2];
    s0 = sv.x; s1 = sv.z; d0 = dv.x; d1 = dv.z;
  }
  int2 rk = *(const int2*)&rank[2 * e2];
  csr[offs[d0] + rk.x] = s0;
  csr[offs[d1] + rk.y] = s1;
}

// ---------------- cast x (f32) -> bf16 h ----------------
__global__ void k_cast(const f32* __restrict__ x, u16* __restrict__ h) {
  int i = blockIdx.x * 256 + threadIdx.x;
  if (i >= N_NODES * 8) return;
  float4 v0 = ((const float4*)x)[i * 2 + 0];
  float4 v1 = ((const float4*)x)[i * 2 + 1];
  us8 r;
  r[0] = f2bf(v0.x); r[1] = f2bf(v0.y); r[2] = f2bf(v0.z); r[3] = f2bf(v0.w);
  r[4] = f2bf(v1.x); r[5] = f2bf(v1.y); r[6] = f2bf(v1.z); r[7] = f2bf(v1.w);
  *(us8*)&h[i * 8] = r;
}

// ---------------- aggregation: wave/node, 8 edge-slots x 8 f-lanes, bf16 ------
__global__ __launch_bounds__(256) void k_agg(const u16* __restrict__ hin,
                                             u16* __restrict__ z,
                                             const int* __restrict__ offs,
                                             const int* __restrict__ csr) {
  int wid = blockIdx.x * 4 + (threadIdx.x >> 6);
  int lane = threadIdx.x & 63;
  int slot = lane >> 3;
  int fl = (lane & 7) << 3;
  int e0 = offs[wid], e1 = offs[wid + 1];
  f32 a0[8] = {0,0,0,0,0,0,0,0};
  f32 a1[8] = {0,0,0,0,0,0,0,0};
  int e = e0 + slot;
  for (; e + 8 < e1; e += 16) {
    int s0 = csr[e], s1 = csr[e + 8];
    us8 v0 = *(const us8*)&hin[s0 * 64 + fl];
    us8 v1 = *(const us8*)&hin[s1 * 64 + fl];
    #pragma unroll
    for (int k = 0; k < 8; ++k) { a0[k] += bf2f(v0[k]); a1[k] += bf2f(v1[k]); }
  }
  if (e < e1) {
    us8 v0 = *(const us8*)&hin[csr[e] * 64 + fl];
    #pragma unroll
    for (int k = 0; k < 8; ++k) a0[k] += bf2f(v0[k]);
  }
  #pragma unroll
  for (int k = 0; k < 8; ++k) a0[k] += a1[k];
  #pragma unroll
  for (int k = 0; k < 8; ++k) {
    a0[k] += __shfl_xor(a0[k], 8);
    a0[k] += __shfl_xor(a0[k], 16);
    a0[k] += __shfl_xor(a0[k], 32);
  }
  if (slot == 0) {
    us8 sv = *(const us8*)&hin[wid * 64 + fl];
    us8 o;
    #pragma unroll
    for (int k = 0; k < 8; ++k) o[k] = f2bf(a0[k] + bf2f(sv[k]));
    *(us8*)&z[wid * 64 + fl] = o;
  }
}

// ---------------- MFMA MLP + BN stats + LDS-transposed coalesced y store ------
__global__ __launch_bounds__(256) void k_mlp(
    const u16* __restrict__ zin, f32* __restrict__ yout,
    const f32* __restrict__ W1, const f32* __restrict__ b1,
    const f32* __restrict__ W2, const f32* __restrict__ b2,
    f32* __restrict__ stsum, f32* __restrict__ stsq)
{
  __shared__ __align__(16) char lds[50176];
  char* zb  = lds;            // 16K bf16 z tile (swizzled); overlaid by y-tile later
  char* w1b = lds + 16384;    // 8K Wt1  (overlaid by y-tile later)
  char* w2b = lds + 24576;    // 8K Wt2  (overlaid by y-tile later)
  char* mb  = lds + 32768;    // 16K mid (per-wave)
  f32* b1s  = (f32*)(lds + 49152);
  f32* b2s  = b1s + 64;
  f32* blks = b2s + 64;
  f32* blkq = blks + 64;
  const int t = threadIdx.x;
  const int base = blockIdx.x * 128;
  // stage z tile (zin padded to 100096 rows)
  #pragma unroll
  for (int r = 0; r < 4; ++r) {
    int off = r * 4096 + t * 16;
    int row = off >> 7, c = off & 127;
    *(us8*)(zb + row * 128 + (c ^ ((row & 7) << 4))) =
        *(const us8*)((const char*)(zin + (size_t)base * 64) + off);
  }
  // stage transposed bf16 weights: Wt[c][k] <- W[k][c]
  #pragma unroll
  for (int i0 = 0; i0 < 16; ++i0) {
    int i = i0 * 256 + t;
    int k = i >> 6, c = i & 63;
    int off = c * 128 + ((k * 2) ^ ((c & 7) << 4));
    *(u16*)(w1b + off) = f2bf(W1[i]);
    *(u16*)(w2b + off) = f2bf(W2[i]);
  }
  if (t < 64) { b1s[t] = b1[t]; b2s[t] = b2[t]; blks[t] = 0.f; blkq[t] = 0.f; }
  __syncthreads();
  const int wv = t >> 6, l = t & 63;
  const int lr = l & 31, lh = l >> 5;
  // ---- GEMM1
  f32x16 acc0, acc1;
  #pragma unroll
  for (int i = 0; i < 16; ++i) { acc0[i] = 0.f; acc1[i] = 0.f; }
  #pragma unroll
  for (int s = 0; s < 4; ++s) {
    int kb = s * 32 + lh * 16;
    int arow = wv * 32 + lr;
    bf16x8 a  = *(bf16x8*)(zb + arow * 128 + (kb ^ ((arow & 7) << 4)));
    bf16x8 bA = *(bf16x8*)(w1b + lr * 128 + (kb ^ ((lr & 7) << 4)));
    bf16x8 bB = *(bf16x8*)(w1b + (lr + 32) * 128 + (kb ^ (((lr + 32) & 7) << 4)));
    acc0 = __builtin_amdgcn_mfma_f32_32x32x16_bf16(a, bA, acc0, 0, 0, 0);
    acc1 = __builtin_amdgcn_mfma_f32_32x32x16_bf16(a, bB, acc1, 0, 0, 0);
  }
  // ---- epilogue1: relu(acc + b1) -> mid (wave-private)
  #pragma unroll
  for (int g = 0; g < 16; ++g) {
    int rowl = (g & 3) + 8 * (g >> 2) + 4 * lh;
    int roff = wv * 4096 + rowl * 128;
    int sw = (rowl & 7) << 4;
    *(u16*)(mb + roff + ((lr * 2) ^ sw))        = f2bf(fmaxf(acc0[g] + b1s[lr], 0.f));
    *(u16*)(mb + roff + (((lr + 32) * 2) ^ sw)) = f2bf(fmaxf(acc1[g] + b1s[lr + 32], 0.f));
  }
  asm volatile("s_waitcnt lgkmcnt(0)" ::: "memory");
  // ---- GEMM2
  #pragma unroll
  for (int i = 0; i < 16; ++i) { acc0[i] = 0.f; acc1[i] = 0.f; }
  #pragma unroll
  for (int s = 0; s < 4; ++s) {
    int kb = s * 32 + lh * 16;
    bf16x8 a  = *(bf16x8*)(mb + wv * 4096 + lr * 128 + (kb ^ ((lr & 7) << 4)));
    bf16x8 bA = *(bf16x8*)(w2b + lr * 128 + (kb ^ ((lr & 7) << 4)));
    bf16x8 bB = *(bf16x8*)(w2b + (lr + 32) * 128 + (kb ^ (((lr + 32) & 7) << 4)));
    acc0 = __builtin_amdgcn_mfma_f32_32x32x16_bf16(a, bA, acc0, 0, 0, 0);
    acc1 = __builtin_amdgcn_mfma_f32_32x32x16_bf16(a, bB, acc1, 0, 0, 0);
  }
  __syncthreads();   // all LDS reads of zb/w1b/w2b done -> safe to overlay with y-tile
  // ---- epilogue2: y = acc + b2 -> wave-private f32 LDS tile + BN partials
  char* yb = lds + wv * 8192;   // 32 rows x 64 f32 = 8KB
  f32 ps0 = 0, pq0 = 0, ps1 = 0, pq1 = 0;
  #pragma unroll
  for (int g = 0; g < 16; ++g) {
    int rowl = (g & 3) + 8 * (g >> 2) + 4 * lh;
    f32 y0 = acc0[g] + b2s[lr];
    f32 y1 = acc1[g] + b2s[lr + 32];
    *(f32*)(yb + rowl * 256 + lr * 4)        = y0;
    *(f32*)(yb + rowl * 256 + (lr + 32) * 4) = y1;
    if (base + wv * 32 + rowl < N_NODES) {
      ps0 += y0; pq0 += y0 * y0;
      ps1 += y1; pq1 += y1 * y1;
    }
  }
  asm volatile("s_waitcnt lgkmcnt(0)" ::: "memory");
  __builtin_amdgcn_sched_barrier(0);
  // coalesced float4 stores
  #pragma unroll
  for (int k = 0; k < 8; ++k) {
    int row = k * 4 + (l >> 4);
    float4 v = *(float4*)(yb + row * 256 + (l & 15) * 16);
    int node = base + wv * 32 + row;
    if (node < N_NODES)
      *(float4*)&yout[(size_t)node * 64 + (l & 15) * 4] = v;
  }
  atomicAdd(&blks[lr], ps0);      atomicAdd(&blkq[lr], pq0);
  atomicAdd(&blks[lr + 32], ps1); atomicAdd(&blkq[lr + 32], pq1);
  __syncthreads();
  if (t < 64) { atomicAdd(&stsum[t], blks[t]); atomicAdd(&stsq[t], blkq[t]); }
}

// ---------------- fused BN finalize + apply + relu -> bf16 h ----------------
__global__ __launch_bounds__(256) void k_bnfin(const f32* __restrict__ y, u16* __restrict__ h,
                                               const f32* __restrict__ st,
                                               const f32* __restrict__ g, const f32* __restrict__ b) {
  __shared__ f32 ss[128];
  int t = threadIdx.x;
  if (t < 64) {
    f32 m = st[t] * (1.f / N_NODES);
    f32 var = st[64 + t] * (1.f / N_NODES) - m * m;
    f32 sc = g[t] * rsqrtf(var + 1e-5f);
    ss[t] = sc; ss[64 + t] = b[t] - m * sc;
  }
  __syncthreads();
  int i = blockIdx.x * 256 + t;
  if (i >= N_NODES * 8) return;
  int c0 = (i & 7) * 8;
  float4 v0 = ((const float4*)y)[i * 2 + 0];
  float4 v1 = ((const float4*)y)[i * 2 + 1];
  us8 r;
  r[0] = f2bf(fmaxf(fmaf(v0.x, ss[c0 + 0], ss[64 + c0 + 0]), 0.f));
  r[1] = f2bf(fmaxf(fmaf(v0.y, ss[c0 + 1], ss[64 + c0 + 1]), 0.f));
  r[2] = f2bf(fmaxf(fmaf(v0.z, ss[c0 + 2], ss[64 + c0 + 2]), 0.f));
  r[3] = f2bf(fmaxf(fmaf(v0.w, ss[c0 + 3], ss[64 + c0 + 3]), 0.f));
  r[4] = f2bf(fmaxf(fmaf(v1.x, ss[c0 + 4], ss[64 + c0 + 4]), 0.f));
  r[5] = f2bf(fmaxf(fmaf(v1.y, ss[c0 + 5], ss[64 + c0 + 5]), 0.f));
  r[6] = f2bf(fmaxf(fmaf(v1.z, ss[c0 + 6], ss[64 + c0 + 6]), 0.f));
  r[7] = f2bf(fmaxf(fmaf(v1.w, ss[c0 + 7], ss[64 + c0 + 7]), 0.f));
  *(us8*)&h[i * 8] = r;
}

// ---------------- pool with fused BN+relu, reads f32 y (batch sorted) ---------
__global__ void k_pool(const f32* __restrict__ y, const int* __restrict__ bw,
                       const int* __restrict__ flag, const f32* __restrict__ st,
                       const f32* __restrict__ g, const f32* __restrict__ b,
                       f32* __restrict__ gsum, f32* __restrict__ gcnt) {
  __shared__ f32 ss[128];
  int t = threadIdx.x;
  if (t < 64) {
    f32 m = st[t] * (1.f / N_NODES);
    f32 var = st[64 + t] * (1.f / N_NODES) - m * m;
    f32 sc = g[t] * rsqrtf(var + 1e-5f);
    ss[t] = sc; ss[64 + t] = b[t] - m * sc;
  }
  __syncthreads();
  int wid = (blockIdx.x * blockDim.x + t) >> 6;
  int lane = t & 63;
  const int nw = (256 * 256) >> 6;
  const int per = (N_NODES + nw - 1) / nw;
  int s = wid * per; int e = s + per; if (e > N_NODES) e = N_NODES;
  if (s >= e) return;
  f32 sc = ss[lane], sh = ss[64 + lane];
  int is32 = flag[0];
  int gcur = is32 ? bw[s] : bw[2 * s];
  f32 acc = 0.f, cnt = 0.f;
  for (int i = s; i < e; ++i) {
    int gi = is32 ? bw[i] : bw[2 * i];
    if (gi != gcur) {
      atomicAdd(&gsum[gcur * 64 + lane], acc);
      if (lane == 0) atomicAdd(&gcnt[gcur], cnt);
      gcur = gi; acc = 0.f; cnt = 0.f;
    }
    acc += fmaxf(fmaf(y[(size_t)i * 64 + lane], sc, sh), 0.f);
    cnt += 1.f;
  }
  atomicAdd(&gsum[gcur * 64 + lane], acc);
  if (lane == 0) atomicAdd(&gcnt[gcur], cnt);
}

// ---------------- head ----------------
__global__ __launch_bounds__(256) void k_head1(const f32* __restrict__ gsum, const f32* __restrict__ gcnt,
                                               const f32* __restrict__ W, const f32* __restrict__ bias,
                                               f32* __restrict__ p, f32* __restrict__ st) {
  __shared__ f32 Ws[4096];
  __shared__ f32 zs[4][64];
  __shared__ f32 bs[64], bq[64];
  int t = threadIdx.x;
  for (int i = t; i < 4096; i += 256) Ws[i] = W[i];
  if (t < 64) { bs[t] = 0.f; bq[t] = 0.f; }
  int wave = t >> 6, lane = t & 63;
  int row = blockIdx.x * 4 + wave;
  f32 z = gsum[row * 64 + lane] / fmaxf(gcnt[row], 1.f);
  zs[wave][lane] = z;
  __syncthreads();
  f32 y = bias[lane];
  for (int f = 0; f < 64; ++f) y = fmaf(zs[wave][f], Ws[f * 64 + lane], y);
  p[row * 64 + lane] = y;
  atomicAdd(&bs[lane], y);
  atomicAdd(&bq[lane], y * y);
  __syncthreads();
  if (t < 64) { atomicAdd(&st[t], bs[t]); atomicAdd(&st[64 + t], bq[t]); }
}

__global__ __launch_bounds__(256) void k_head2(const f32* __restrict__ p1, const f32* __restrict__ st,
                                               const f32* __restrict__ g, const f32* __restrict__ b,
                                               const f32* __restrict__ W, const f32* __restrict__ bias,
                                               f32* __restrict__ p2, f32* __restrict__ st2) {
  __shared__ f32 Ws[2048];
  __shared__ f32 zs[4][64];
  __shared__ f32 bs[32], bq[32];
  __shared__ f32 ss[128];
  int t = threadIdx.x;
  for (int i = t; i < 2048; i += 256) Ws[i] = W[i];
  if (t < 64) {
    f32 m = st[t] * (1.f / NG);
    f32 var = st[64 + t] * (1.f / NG) - m * m;
    f32 sc = g[t] * rsqrtf(var + 1e-5f);
    ss[t] = sc; ss[64 + t] = b[t] - m * sc;
  }
  if (t < 32) { bs[t] = 0.f; bq[t] = 0.f; }
  __syncthreads();
  int wave = t >> 6, lane = t & 63;
  int row = blockIdx.x * 4 + wave;
  f32 z = fmaxf(fmaf(p1[row * 64 + lane], ss[lane], ss[64 + lane]), 0.f);
  zs[wave][lane] = z;
  __syncthreads();
  if (lane < 32) {
    f32 y = bias[lane];
    for (int f = 0; f < 64; ++f) y = fmaf(zs[wave][f], Ws[f * 32 + lane], y);
    p2[row * 32 + lane] = y;
    atomicAdd(&bs[lane], y);
    atomicAdd(&bq[lane], y * y);
  }
  __syncthreads();
  if (t < 32) { atomicAdd(&st2[t], bs[t]); atomicAdd(&st2[64 + t], bq[t]); }
}

__global__ __launch_bounds__(256) void k_head3(const f32* __restrict__ p2, const f32* __restrict__ st2,
                                               const f32* __restrict__ g, const f32* __restrict__ b,
                                               const f32* __restrict__ W, const f32* __restrict__ bias,
                                               f32* __restrict__ out) {
  __shared__ f32 Ws[320];
  __shared__ f32 obs[10];
  __shared__ f32 zs[4][32];
  __shared__ f32 ss[64];
  int t = threadIdx.x;
  for (int i = t; i < 320; i += 256) Ws[i] = W[i];
  if (t < 10) obs[t] = bias[t];
  if (t < 32) {
    f32 m = st2[t] * (1.f / NG);
    f32 var = st2[64 + t] * (1.f / NG) - m * m;
    f32 sc = g[t] * rsqrtf(var + 1e-5f);
    ss[t] = sc; ss[32 + t] = b[t] - m * sc;
  }
  __syncthreads();
  int wave = t >> 6, lane = t & 63;
  int row = blockIdx.x * 4 + wave;
  if (lane < 32) zs[wave][lane] = fmaxf(fmaf(p2[row * 32 + lane], ss[lane], ss[32 + lane]), 0.f);
  __syncthreads();
  if (lane < 10) {
    f32 o = obs[lane];
    for (int f = 0; f < 32; ++f) o = fmaf(zs[wave][f], Ws[f * 10 + lane], o);
    out[row * 10 + lane] = o;
  }
}

extern "C" void kernel_launch(void* const* d_in, const int* in_sizes, int n_in,
                              void* d_out, int out_size, void* d_ws, size_t ws_size,
                              hipStream_t stream) {
  (void)in_sizes; (void)n_in; (void)out_size; (void)ws_size;
  const f32* x    = (const f32*)d_in[0];
  const int* eiw  = (const int*)d_in[1];
  const int* btw  = (const int*)d_in[2];
  const f32* mw1  = (const f32*)d_in[3];
  const f32* mb1  = (const f32*)d_in[4];
  const f32* mw2  = (const f32*)d_in[5];
  const f32* mb2  = (const f32*)d_in[6];
  const f32* bng  = (const f32*)d_in[7];
  const f32* bnb  = (const f32*)d_in[8];
  const f32* hw1  = (const f32*)d_in[9];
  const f32* hb1  = (const f32*)d_in[10];
  const f32* hg1  = (const f32*)d_in[11];
  const f32* hbb1 = (const f32*)d_in[12];
  const f32* hw2  = (const f32*)d_in[13];
  const f32* hb2  = (const f32*)d_in[14];
  const f32* hg2  = (const f32*)d_in[15];
  const f32* hbb2 = (const f32*)d_in[16];
  const f32* ow   = (const f32*)d_in[17];
  const f32* ob   = (const f32*)d_in[18];
  f32* out = (f32*)d_out;

  // ---- zeroed region (one memset): deg, flag, stats, gsum, gcnt ----
  int* deg   = (int*)d_ws;             // 100000
  int* flag  = deg + 100000;           // 32 (padded)
  f32* stats = (f32*)(flag + 32);      // 1024
  f32* gsum  = stats + 1024;           // NG*64 = 32768
  f32* gcnt  = gsum + NG * 64;         // 512
  const size_t ZERO_INTS = 100000 + 32 + 1024 + 32768 + 512;  // 134336
  // ---- rest ----
  int* incl  = (int*)(gcnt + NG);      // 100000
  int* bsums = incl + 100000;          // 128
  int* offs  = bsums + 128;            // 100004
  int* rank  = offs + 100004;          // 1200000
  int* csr   = rank + N_EDGES;         // 1200000
  u16* hbuf  = (u16*)(csr + N_EDGES);          // 6.4M u16
  u16* zbuf  = hbuf + (size_t)N_NODES * 64;    // 100096*64 u16 (padded tile reads)
  f32* ybuf  = (f32*)(zbuf + (size_t)100096 * 64);  // 6.4M f32
  f32* p1    = ybuf + (size_t)N_NODES * 64;    // NG*64
  f32* p2    = p1 + NG * 64;                   // NG*32

  hipMemsetAsync(deg, 0, ZERO_INTS * sizeof(int), stream);

  k_detect<<<1, 256, 0, stream>>>(eiw, flag);
  k_count<<<(N_EDGES / 2 + 255) / 256, 256, 0, stream>>>(eiw, flag, deg, rank);
  k_scan1<<<(N_NODES + 1023) / 1024, 256, 0, stream>>>(deg, incl, bsums);
  k_scan2<<<1, 128, 0, stream>>>(bsums, (N_NODES + 1023) / 1024);
  k_scan3<<<(N_NODES + 255) / 256, 256, 0, stream>>>(incl, bsums, offs);
  k_fill<<<(N_EDGES / 2 + 255) / 256, 256, 0, stream>>>(eiw, flag, offs, rank, csr);

  const int AGG_GRID = N_NODES / 4;
  const int MLP_GRID = (N_NODES + 127) / 128;
  const int C8_GRID  = (N_NODES * 8 + 255) / 256;

  k_cast<<<C8_GRID, 256, 0, stream>>>(x, hbuf);
  // layer 0
  k_agg<<<AGG_GRID, 256, 0, stream>>>(hbuf, zbuf, offs, csr);
  k_mlp<<<MLP_GRID, 256, 0, stream>>>(zbuf, ybuf, mw1, mb1, mw2, mb2, stats + 0, stats + 64);
  k_bnfin<<<C8_GRID, 256, 0, stream>>>(ybuf, hbuf, stats + 0, bng + 0, bnb + 0);
  // layer 1
  k_agg<<<AGG_GRID, 256, 0, stream>>>(hbuf, zbuf, offs, csr);
  k_mlp<<<MLP_GRID, 256, 0, stream>>>(zbuf, ybuf, mw1 + 4096, mb1 + 64, mw2 + 4096, mb2 + 64, stats + 128, stats + 192);
  k_bnfin<<<C8_GRID, 256, 0, stream>>>(ybuf, hbuf, stats + 128, bng + 64, bnb + 64);
  // layer 2 (BN fused into pool)
  k_agg<<<AGG_GRID, 256, 0, stream>>>(hbuf, zbuf, offs, csr);
  k_mlp<<<MLP_GRID, 256, 0, stream>>>(zbuf, ybuf, mw1 + 8192, mb1 + 128, mw2 + 8192, mb2 + 128, stats + 256, stats + 320);

  k_pool<<<256, 256, 0, stream>>>(ybuf, btw, flag, stats + 256, bng + 128, bnb + 128, gsum, gcnt);
  k_head1<<<NG / 4, 256, 0, stream>>>(gsum, gcnt, hw1, hb1, p1, stats + 384);
  k_head2<<<NG / 4, 256, 0, stream>>>(p1, stats + 384, hg1, hbb1, hw2, hb2, p2, stats + 512);
  k_head3<<<NG / 4, 256, 0, stream>>>(p2, stats + 512, hg2, hbb2, ow, ob, out);
}

// Round 10
// 453.336 us; speedup vs baseline: 2.9810x; 1.0725x over previous
//
#include <hip/hip_runtime.h>
#include <hip/hip_bf16.h>

#define N_NODES 100000
#define N_EDGES 1200000
#define NG 512
#define NB 512
#define SPAN 196          // ceil(N_NODES/NB)
#define BCAP 3000         // bucket capacity (mean 2352, sd 48 -> +13 sigma)

typedef float f32;
typedef unsigned short u16;
typedef unsigned short us8 __attribute__((ext_vector_type(8)));
typedef __bf16 bf16x8 __attribute__((ext_vector_type(8)));
typedef float f32x16 __attribute__((ext_vector_type(16)));

__device__ __forceinline__ f32 bf2f(u16 v) {
  return __uint_as_float(((unsigned)v) << 16);
}
__device__ __forceinline__ u16 f2bf(f32 f) {
  __hip_bfloat16 b = __float2bfloat16(f);   // RNE
  return *reinterpret_cast<u16*>(&b);
}

// ---------------- dtype probe + bucket cursor init ----------------
__global__ void k_detect(const int* __restrict__ w, int* __restrict__ flag,
                         int* __restrict__ bcur) {
  int t = threadIdx.x;   // 512
  if (t < 256) {
    int acc = 0;
    #pragma unroll
    for (int k = 0; k < 8; ++k) acc |= w[(t * 8 + k) * 2 + 1];
    if (acc) atomicOr(flag, 1);
  }
  bcur[t] = t * BCAP;
}

// ---------------- P1: bucket-scatter edges (LDS hist + run reservation) -------
__global__ __launch_bounds__(256) void k_bscatter(const int* __restrict__ w,
                                                  const int* __restrict__ flag,
                                                  int* __restrict__ bcur,
                                                  int* __restrict__ ssrc,
                                                  u16* __restrict__ sld) {
  __shared__ int bins[NB];
  __shared__ int lbase[NB];
  const int t = threadIdx.x;
  for (int i = t; i < NB; i += 256) bins[i] = 0;
  __syncthreads();
  const int per = (N_EDGES + 255) / 256;           // 4688 edges/block
  int e0 = blockIdx.x * per;
  int e1 = e0 + per; if (e1 > N_EDGES) e1 = N_EDGES;
  const int is32 = flag[0];
  for (int e = e0 + t; e < e1; e += 256) {
    int d = is32 ? w[N_EDGES + e] : w[2 * (N_EDGES + e)];
    atomicAdd(&bins[d / SPAN], 1);
  }
  __syncthreads();
  for (int i = t; i < NB; i += 256) {
    int c = bins[i];
    lbase[i] = c ? atomicAdd(&bcur[i], c) : 0;
  }
  __syncthreads();
  for (int i = t; i < NB; i += 256) bins[i] = 0;
  __syncthreads();
  for (int e = e0 + t; e < e1; e += 256) {
    int s, d;
    if (is32) { s = w[e];     d = w[N_EDGES + e]; }
    else      { s = w[2 * e]; d = w[2 * (N_EDGES + e)]; }
    int b = d / SPAN;
    int r = atomicAdd(&bins[b], 1);
    int slot = lbase[b] + r;
    ssrc[slot] = s;
    sld[slot]  = (u16)(d - b * SPAN);
  }
}

// ---------------- P2: scan bucket counts -> dense csr bases ----------------
__global__ void k_bscan(const int* __restrict__ bcur, int* __restrict__ bbase) {
  __shared__ int sd[NB];
  int t = threadIdx.x;   // 512
  int c = bcur[t] - t * BCAP;
  sd[t] = c; __syncthreads();
  for (int off = 1; off < NB; off <<= 1) {
    int x = (t >= off) ? sd[t - off] : 0; __syncthreads();
    sd[t] += x; __syncthreads();
  }
  bbase[t] = sd[t] - c;
  if (t == NB - 1) bbase[NB] = sd[t];
}

// ---------------- P3: per-bucket counting sort -> csr + offs ----------------
__global__ __launch_bounds__(256) void k_bsort(const int* __restrict__ bcur,
                                               const int* __restrict__ bbase,
                                               const int* __restrict__ ssrc,
                                               const u16* __restrict__ sld,
                                               int* __restrict__ csr,
                                               int* __restrict__ offs) {
  __shared__ int hist[256];
  __shared__ int cur[SPAN];
  const int b = blockIdx.x, t = threadIdx.x;
  const int sbase = b * BCAP;
  const int cnt = bcur[b] - sbase;
  const int ebase = bbase[b];
  hist[t] = 0;
  __syncthreads();
  for (int i = t; i < cnt; i += 256) atomicAdd(&hist[sld[sbase + i]], 1);
  __syncthreads();
  int v0 = hist[t]; __syncthreads();
  for (int off = 1; off < 256; off <<= 1) {
    int x = (t >= off) ? hist[t - off] : 0; __syncthreads();
    hist[t] += x; __syncthreads();
  }
  int excl = hist[t] - v0;
  int node = b * SPAN + t;
  if (t < SPAN) {
    cur[t] = excl;
    if (node < N_NODES) offs[node] = ebase + excl;
  }
  if (b == NB - 1 && t == 0) offs[N_NODES] = ebase + cnt;
  __syncthreads();
  for (int i = t; i < cnt; i += 256) {
    int ld = sld[sbase + i];
    int r = atomicAdd(&cur[ld], 1);
    csr[ebase + r] = ssrc[sbase + i];
  }
}

// ---------------- cast x (f32) -> bf16 h ----------------
__global__ void k_cast(const f32* __restrict__ x, u16* __restrict__ h) {
  int i = blockIdx.x * 256 + threadIdx.x;
  if (i >= N_NODES * 8) return;
  float4 v0 = ((const float4*)x)[i * 2 + 0];
  float4 v1 = ((const float4*)x)[i * 2 + 1];
  us8 r;
  r[0] = f2bf(v0.x); r[1] = f2bf(v0.y); r[2] = f2bf(v0.z); r[3] = f2bf(v0.w);
  r[4] = f2bf(v1.x); r[5] = f2bf(v1.y); r[6] = f2bf(v1.z); r[7] = f2bf(v1.w);
  *(us8*)&h[i * 8] = r;
}

// ---------------- aggregation: wave/node, 8 edge-slots x 8 f-lanes, bf16 ------
__global__ __launch_bounds__(256) void k_agg(const u16* __restrict__ hin,
                                             u16* __restrict__ z,
                                             const int* __restrict__ offs,
                                             const int* __restrict__ csr) {
  int wid = blockIdx.x * 4 + (threadIdx.x >> 6);
  int lane = threadIdx.x & 63;
  int slot = lane >> 3;
  int fl = (lane & 7) << 3;
  int e0 = offs[wid], e1 = offs[wid + 1];
  f32 a0[8] = {0,0,0,0,0,0,0,0};
  f32 a1[8] = {0,0,0,0,0,0,0,0};
  int e = e0 + slot;
  for (; e + 8 < e1; e += 16) {
    int s0 = csr[e], s1 = csr[e + 8];
    us8 v0 = *(const us8*)&hin[s0 * 64 + fl];
    us8 v1 = *(const us8*)&hin[s1 * 64 + fl];
    #pragma unroll
    for (int k = 0; k < 8; ++k) { a0[k] += bf2f(v0[k]); a1[k] += bf2f(v1[k]); }
  }
  if (e < e1) {
    us8 v0 = *(const us8*)&hin[csr[e] * 64 + fl];
    #pragma unroll
    for (int k = 0; k < 8; ++k) a0[k] += bf2f(v0[k]);
  }
  #pragma unroll
  for (int k = 0; k < 8; ++k) a0[k] += a1[k];
  #pragma unroll
  for (int k = 0; k < 8; ++k) {
    a0[k] += __shfl_xor(a0[k], 8);
    a0[k] += __shfl_xor(a0[k], 16);
    a0[k] += __shfl_xor(a0[k], 32);
  }
  if (slot == 0) {
    us8 sv = *(const us8*)&hin[wid * 64 + fl];
    us8 o;
    #pragma unroll
    for (int k = 0; k < 8; ++k) o[k] = f2bf(a0[k] + bf2f(sv[k]));
    *(us8*)&z[wid * 64 + fl] = o;
  }
}

// ---------------- MFMA MLP + BN stats + LDS-transposed coalesced y store ------
__global__ __launch_bounds__(256) void k_mlp(
    const u16* __restrict__ zin, f32* __restrict__ yout,
    const f32* __restrict__ W1, const f32* __restrict__ b1,
    const f32* __restrict__ W2, const f32* __restrict__ b2,
    f32* __restrict__ stsum, f32* __restrict__ stsq)
{
  __shared__ __align__(16) char lds[50176];
  char* zb  = lds;
  char* w1b = lds + 16384;
  char* w2b = lds + 24576;
  char* mb  = lds + 32768;
  f32* b1s  = (f32*)(lds + 49152);
  f32* b2s  = b1s + 64;
  f32* blks = b2s + 64;
  f32* blkq = blks + 64;
  const int t = threadIdx.x;
  const int base = blockIdx.x * 128;
  #pragma unroll
  for (int r = 0; r < 4; ++r) {
    int off = r * 4096 + t * 16;
    int row = off >> 7, c = off & 127;
    *(us8*)(zb + row * 128 + (c ^ ((row & 7) << 4))) =
        *(const us8*)((const char*)(zin + (size_t)base * 64) + off);
  }
  #pragma unroll
  for (int i0 = 0; i0 < 16; ++i0) {
    int i = i0 * 256 + t;
    int k = i >> 6, c = i & 63;
    int off = c * 128 + ((k * 2) ^ ((c & 7) << 4));
    *(u16*)(w1b + off) = f2bf(W1[i]);
    *(u16*)(w2b + off) = f2bf(W2[i]);
  }
  if (t < 64) { b1s[t] = b1[t]; b2s[t] = b2[t]; blks[t] = 0.f; blkq[t] = 0.f; }
  __syncthreads();
  const int wv = t >> 6, l = t & 63;
  const int lr = l & 31, lh = l >> 5;
  f32x16 acc0, acc1;
  #pragma unroll
  for (int i = 0; i < 16; ++i) { acc0[i] = 0.f; acc1[i] = 0.f; }
  #pragma unroll
  for (int s = 0; s < 4; ++s) {
    int kb = s * 32 + lh * 16;
    int arow = wv * 32 + lr;
    bf16x8 a  = *(bf16x8*)(zb + arow * 128 + (kb ^ ((arow & 7) << 4)));
    bf16x8 bA = *(bf16x8*)(w1b + lr * 128 + (kb ^ ((lr & 7) << 4)));
    bf16x8 bB = *(bf16x8*)(w1b + (lr + 32) * 128 + (kb ^ (((lr + 32) & 7) << 4)));
    acc0 = __builtin_amdgcn_mfma_f32_32x32x16_bf16(a, bA, acc0, 0, 0, 0);
    acc1 = __builtin_amdgcn_mfma_f32_32x32x16_bf16(a, bB, acc1, 0, 0, 0);
  }
  #pragma unroll
  for (int g = 0; g < 16; ++g) {
    int rowl = (g & 3) + 8 * (g >> 2) + 4 * lh;
    int roff = wv * 4096 + rowl * 128;
    int sw = (rowl & 7) << 4;
    *(u16*)(mb + roff + ((lr * 2) ^ sw))        = f2bf(fmaxf(acc0[g] + b1s[lr], 0.f));
    *(u16*)(mb + roff + (((lr + 32) * 2) ^ sw)) = f2bf(fmaxf(acc1[g] + b1s[lr + 32], 0.f));
  }
  asm volatile("s_waitcnt lgkmcnt(0)" ::: "memory");
  #pragma unroll
  for (int i = 0; i < 16; ++i) { acc0[i] = 0.f; acc1[i] = 0.f; }
  #pragma unroll
  for (int s = 0; s < 4; ++s) {
    int kb = s * 32 + lh * 16;
    bf16x8 a  = *(bf16x8*)(mb + wv * 4096 + lr * 128 + (kb ^ ((lr & 7) << 4)));
    bf16x8 bA = *(bf16x8*)(w2b + lr * 128 + (kb ^ ((lr & 7) << 4)));
    bf16x8 bB = *(bf16x8*)(w2b + (lr + 32) * 128 + (kb ^ (((lr + 32) & 7) << 4)));
    acc0 = __builtin_amdgcn_mfma_f32_32x32x16_bf16(a, bA, acc0, 0, 0, 0);
    acc1 = __builtin_amdgcn_mfma_f32_32x32x16_bf16(a, bB, acc1, 0, 0, 0);
  }
  __syncthreads();
  char* yb = lds + wv * 8192;
  f32 ps0 = 0, pq0 = 0, ps1 = 0, pq1 = 0;
  #pragma unroll
  for (int g = 0; g < 16; ++g) {
    int rowl = (g & 3) + 8 * (g >> 2) + 4 * lh;
    f32 y0 = acc0[g] + b2s[lr];
    f32 y1 = acc1[g] + b2s[lr + 32];
    *(f32*)(yb + rowl * 256 + lr * 4)        = y0;
    *(f32*)(yb + rowl * 256 + (lr + 32) * 4) = y1;
    if (base + wv * 32 + rowl < N_NODES) {
      ps0 += y0; pq0 += y0 * y0;
      ps1 += y1; pq1 += y1 * y1;
    }
  }
  asm volatile("s_waitcnt lgkmcnt(0)" ::: "memory");
  __builtin_amdgcn_sched_barrier(0);
  #pragma unroll
  for (int k = 0; k < 8; ++k) {
    int row = k * 4 + (l >> 4);
    float4 v = *(float4*)(yb + row * 256 + (l & 15) * 16);
    int node = base + wv * 32 + row;
    if (node < N_NODES)
      *(float4*)&yout[(size_t)node * 64 + (l & 15) * 4] = v;
  }
  atomicAdd(&blks[lr], ps0);      atomicAdd(&blkq[lr], pq0);
  atomicAdd(&blks[lr + 32], ps1); atomicAdd(&blkq[lr + 32], pq1);
  __syncthreads();
  if (t < 64) { atomicAdd(&stsum[t], blks[t]); atomicAdd(&stsq[t], blkq[t]); }
}

// ---------------- fused BN finalize + apply + relu -> bf16 h ----------------
__global__ __launch_bounds__(256) void k_bnfin(const f32* __restrict__ y, u16* __restrict__ h,
                                               const f32* __restrict__ st,
                                               const f32* __restrict__ g, const f32* __restrict__ b) {
  __shared__ f32 ss[128];
  int t = threadIdx.x;
  if (t < 64) {
    f32 m = st[t] * (1.f / N_NODES);
    f32 var = st[64 + t] * (1.f / N_NODES) - m * m;
    f32 sc = g[t] * rsqrtf(var + 1e-5f);
    ss[t] = sc; ss[64 + t] = b[t] - m * sc;
  }
  __syncthreads();
  int i = blockIdx.x * 256 + t;
  if (i >= N_NODES * 8) return;
  int c0 = (i & 7) * 8;
  float4 v0 = ((const float4*)y)[i * 2 + 0];
  float4 v1 = ((const float4*)y)[i * 2 + 1];
  us8 r;
  r[0] = f2bf(fmaxf(fmaf(v0.x, ss[c0 + 0], ss[64 + c0 + 0]), 0.f));
  r[1] = f2bf(fmaxf(fmaf(v0.y, ss[c0 + 1], ss[64 + c0 + 1]), 0.f));
  r[2] = f2bf(fmaxf(fmaf(v0.z, ss[c0 + 2], ss[64 + c0 + 2]), 0.f));
  r[3] = f2bf(fmaxf(fmaf(v0.w, ss[c0 + 3], ss[64 + c0 + 3]), 0.f));
  r[4] = f2bf(fmaxf(fmaf(v1.x, ss[c0 + 4], ss[64 + c0 + 4]), 0.f));
  r[5] = f2bf(fmaxf(fmaf(v1.y, ss[c0 + 5], ss[64 + c0 + 5]), 0.f));
  r[6] = f2bf(fmaxf(fmaf(v1.z, ss[c0 + 6], ss[64 + c0 + 6]), 0.f));
  r[7] = f2bf(fmaxf(fmaf(v1.w, ss[c0 + 7], ss[64 + c0 + 7]), 0.f));
  *(us8*)&h[i * 8] = r;
}

// ---------------- pool with fused BN+relu, reads f32 y (batch sorted) ---------
__global__ void k_pool(const f32* __restrict__ y, const int* __restrict__ bw,
                       const int* __restrict__ flag, const f32* __restrict__ st,
                       const f32* __restrict__ g, const f32* __restrict__ b,
                       f32* __restrict__ gsum, f32* __restrict__ gcnt) {
  __shared__ f32 ss[128];
  int t = threadIdx.x;
  if (t < 64) {
    f32 m = st[t] * (1.f / N_NODES);
    f32 var = st[64 + t] * (1.f / N_NODES) - m * m;
    f32 sc = g[t] * rsqrtf(var + 1e-5f);
    ss[t] = sc; ss[64 + t] = b[t] - m * sc;
  }
  __syncthreads();
  int wid = (blockIdx.x * blockDim.x + t) >> 6;
  int lane = t & 63;
  const int nw = (256 * 256) >> 6;
  const int per = (N_NODES + nw - 1) / nw;
  int s = wid * per; int e = s + per; if (e > N_NODES) e = N_NODES;
  if (s >= e) return;
  f32 sc = ss[lane], sh = ss[64 + lane];
  int is32 = flag[0];
  int gcur = is32 ? bw[s] : bw[2 * s];
  f32 acc = 0.f, cnt = 0.f;
  for (int i = s; i < e; ++i) {
    int gi = is32 ? bw[i] : bw[2 * i];
    if (gi != gcur) {
      atomicAdd(&gsum[gcur * 64 + lane], acc);
      if (lane == 0) atomicAdd(&gcnt[gcur], cnt);
      gcur = gi; acc = 0.f; cnt = 0.f;
    }
    acc += fmaxf(fmaf(y[(size_t)i * 64 + lane], sc, sh), 0.f);
    cnt += 1.f;
  }
  atomicAdd(&gsum[gcur * 64 + lane], acc);
  if (lane == 0) atomicAdd(&gcnt[gcur], cnt);
}

// ---------------- head ----------------
__global__ __launch_bounds__(256) void k_head1(const f32* __restrict__ gsum, const f32* __restrict__ gcnt,
                                               const f32* __restrict__ W, const f32* __restrict__ bias,
                                               f32* __restrict__ p, f32* __restrict__ st) {
  __shared__ f32 Ws[4096];
  __shared__ f32 zs[4][64];
  __shared__ f32 bs[64], bq[64];
  int t = threadIdx.x;
  for (int i = t; i < 4096; i += 256) Ws[i] = W[i];
  if (t < 64) { bs[t] = 0.f; bq[t] = 0.f; }
  int wave = t >> 6, lane = t & 63;
  int row = blockIdx.x * 4 + wave;
  f32 z = gsum[row * 64 + lane] / fmaxf(gcnt[row], 1.f);
  zs[wave][lane] = z;
  __syncthreads();
  f32 y = bias[lane];
  for (int f = 0; f < 64; ++f) y = fmaf(zs[wave][f], Ws[f * 64 + lane], y);
  p[row * 64 + lane] = y;
  atomicAdd(&bs[lane], y);
  atomicAdd(&bq[lane], y * y);
  __syncthreads();
  if (t < 64) { atomicAdd(&st[t], bs[t]); atomicAdd(&st[64 + t], bq[t]); }
}

__global__ __launch_bounds__(256) void k_head2(const f32* __restrict__ p1, const f32* __restrict__ st,
                                               const f32* __restrict__ g, const f32* __restrict__ b,
                                               const f32* __restrict__ W, const f32* __restrict__ bias,
                                               f32* __restrict__ p2, f32* __restrict__ st2) {
  __shared__ f32 Ws[2048];
  __shared__ f32 zs[4][64];
  __shared__ f32 bs[32], bq[32];
  __shared__ f32 ss[128];
  int t = threadIdx.x;
  for (int i = t; i < 2048; i += 256) Ws[i] = W[i];
  if (t < 64) {
    f32 m = st[t] * (1.f / NG);
    f32 var = st[64 + t] * (1.f / NG) - m * m;
    f32 sc = g[t] * rsqrtf(var + 1e-5f);
    ss[t] = sc; ss[64 + t] = b[t] - m * sc;
  }
  if (t < 32) { bs[t] = 0.f; bq[t] = 0.f; }
  __syncthreads();
  int wave = t >> 6, lane = t & 63;
  int row = blockIdx.x * 4 + wave;
  f32 z = fmaxf(fmaf(p1[row * 64 + lane], ss[lane], ss[64 + lane]), 0.f);
  zs[wave][lane] = z;
  __syncthreads();
  if (lane < 32) {
    f32 y = bias[lane];
    for (int f = 0; f < 64; ++f) y = fmaf(zs[wave][f], Ws[f * 32 + lane], y);
    p2[row * 32 + lane] = y;
    atomicAdd(&bs[lane], y);
    atomicAdd(&bq[lane], y * y);
  }
  __syncthreads();
  if (t < 32) { atomicAdd(&st2[t], bs[t]); atomicAdd(&st2[64 + t], bq[t]); }
}

__global__ __launch_bounds__(256) void k_head3(const f32* __restrict__ p2, const f32* __restrict__ st2,
                                               const f32* __restrict__ g, const f32* __restrict__ b,
                                               const f32* __restrict__ W, const f32* __restrict__ bias,
                                               f32* __restrict__ out) {
  __shared__ f32 Ws[320];
  __shared__ f32 obs[10];
  __shared__ f32 zs[4][32];
  __shared__ f32 ss[64];
  int t = threadIdx.x;
  for (int i = t; i < 320; i += 256) Ws[i] = W[i];
  if (t < 10) obs[t] = bias[t];
  if (t < 32) {
    f32 m = st2[t] * (1.f / NG);
    f32 var = st2[64 + t] * (1.f / NG) - m * m;
    f32 sc = g[t] * rsqrtf(var + 1e-5f);
    ss[t] = sc; ss[32 + t] = b[t] - m * sc;
  }
  __syncthreads();
  int wave = t >> 6, lane = t & 63;
  int row = blockIdx.x * 4 + wave;
  if (lane < 32) zs[wave][lane] = fmaxf(fmaf(p2[row * 32 + lane], ss[lane], ss[32 + lane]), 0.f);
  __syncthreads();
  if (lane < 10) {
    f32 o = obs[lane];
    for (int f = 0; f < 32; ++f) o = fmaf(zs[wave][f], Ws[f * 10 + lane], o);
    out[row * 10 + lane] = o;
  }
}

extern "C" void kernel_launch(void* const* d_in, const int* in_sizes, int n_in,
                              void* d_out, int out_size, void* d_ws, size_t ws_size,
                              hipStream_t stream) {
  (void)in_sizes; (void)n_in; (void)out_size; (void)ws_size;
  const f32* x    = (const f32*)d_in[0];
  const int* eiw  = (const int*)d_in[1];
  const int* btw  = (const int*)d_in[2];
  const f32* mw1  = (const f32*)d_in[3];
  const f32* mb1  = (const f32*)d_in[4];
  const f32* mw2  = (const f32*)d_in[5];
  const f32* mb2  = (const f32*)d_in[6];
  const f32* bng  = (const f32*)d_in[7];
  const f32* bnb  = (const f32*)d_in[8];
  const f32* hw1  = (const f32*)d_in[9];
  const f32* hb1  = (const f32*)d_in[10];
  const f32* hg1  = (const f32*)d_in[11];
  const f32* hbb1 = (const f32*)d_in[12];
  const f32* hw2  = (const f32*)d_in[13];
  const f32* hb2  = (const f32*)d_in[14];
  const f32* hg2  = (const f32*)d_in[15];
  const f32* hbb2 = (const f32*)d_in[16];
  const f32* ow   = (const f32*)d_in[17];
  const f32* ob   = (const f32*)d_in[18];
  f32* out = (f32*)d_out;

  // ---- zeroed region (one memset): flag, stats, gsum, gcnt ----
  int* flag  = (int*)d_ws;             // 32
  f32* stats = (f32*)(flag + 32);      // 1024
  f32* gsum  = stats + 1024;           // NG*64
  f32* gcnt  = gsum + NG * 64;         // 512
  const size_t ZERO_INTS = 32 + 1024 + NG * 64 + NG;   // 34336
  // ---- rest ----
  int* bcur  = (int*)(gcnt + NG);      // 512 (init by k_detect)
  int* bbase = bcur + NB;              // 513 -> pad 516
  int* offs  = bbase + 516;            // 100004
  int* ssrc  = offs + 100004;          // NB*BCAP = 1,536,000
  u16* sldv  = (u16*)(ssrc + NB * BCAP);               // 1,536,000 u16
  int* csr   = (int*)(sldv + NB * BCAP);               // 1,200,000
  u16* hbuf  = (u16*)(csr + N_EDGES);                  // 6.4M u16 (16B-aligned)
  u16* zbuf  = hbuf + (size_t)N_NODES * 64;            // 100096*64 u16 (padded)
  f32* ybuf  = (f32*)(zbuf + (size_t)100096 * 64);     // 6.4M f32
  f32* p1    = ybuf + (size_t)N_NODES * 64;            // NG*64
  f32* p2    = p1 + NG * 64;                           // NG*32

  hipMemsetAsync(flag, 0, ZERO_INTS * sizeof(int), stream);

  k_detect<<<1, 512, 0, stream>>>(eiw, flag, bcur);
  k_bscatter<<<256, 256, 0, stream>>>(eiw, flag, bcur, ssrc, sldv);
  k_bscan<<<1, NB, 0, stream>>>(bcur, bbase);
  k_bsort<<<NB, 256, 0, stream>>>(bcur, bbase, ssrc, sldv, csr, offs);

  const int AGG_GRID = N_NODES / 4;
  const int MLP_GRID = (N_NODES + 127) / 128;
  const int C8_GRID  = (N_NODES * 8 + 255) / 256;

  k_cast<<<C8_GRID, 256, 0, stream>>>(x, hbuf);
  // layer 0
  k_agg<<<AGG_GRID, 256, 0, stream>>>(hbuf, zbuf, offs, csr);
  k_mlp<<<MLP_GRID, 256, 0, stream>>>(zbuf, ybuf, mw1, mb1, mw2, mb2, stats + 0, stats + 64);
  k_bnfin<<<C8_GRID, 256, 0, stream>>>(ybuf, hbuf, stats + 0, bng + 0, bnb + 0);
  // layer 1
  k_agg<<<AGG_GRID, 256, 0, stream>>>(hbuf, zbuf, offs, csr);
  k_mlp<<<MLP_GRID, 256, 0, stream>>>(zbuf, ybuf, mw1 + 4096, mb1 + 64, mw2 + 4096, mb2 + 64, stats + 128, stats + 192);
  k_bnfin<<<C8_GRID, 256, 0, stream>>>(ybuf, hbuf, stats + 128, bng + 64, bnb + 64);
  // layer 2 (BN fused into pool)
  k_agg<<<AGG_GRID, 256, 0, stream>>>(hbuf, zbuf, offs, csr);
  k_mlp<<<MLP_GRID, 256, 0, stream>>>(zbuf, ybuf, mw1 + 8192, mb1 + 128, mw2 + 8192, mb2 + 128, stats + 256, stats + 320);

  k_pool<<<256, 256, 0, stream>>>(ybuf, btw, flag, stats + 256, bng + 128, bnb + 128, gsum, gcnt);
  k_head1<<<NG / 4, 256, 0, stream>>>(gsum, gcnt, hw1, hb1, p1, stats + 384);
  k_head2<<<NG / 4, 256, 0, stream>>>(p1, stats + 384, hg1, hbb1, hw2, hb2, p2, stats + 512);
  k_head3<<<NG / 4, 256, 0, stream>>>(p2, stats + 512, hg2, hbb2, ow, ob, out);
}